// Round 11
// baseline (296.679 us; speedup 1.0000x reference)
//
#include <hip/hip_runtime.h>
#include <hip/hip_bf16.h>

// DA-RNN persistent kernel, round 17: occupancy-gated BB=2 co-residency.
// R16 confirmed (204us). Remaining ~40% stall = unhidden DS-latency on the
// critical wave (1 wave/SIMD on each phase's pole chain). Fix needs a
// SECOND independent chain per CU: grid > #CUs (BB=2, grid 512) + LDS<=80KB
// + total regs<=128 (R8: 108arch+~24acc = tier256 = why occupancy stuck).
// R17: template<NB> kernel. NB=2: bounds(512,4), LDS ~81.4KB (halved
// projT/encht/gates/base/beta; per-wave scratch compacted), register diet
// (Lagrange d recomputed on the fly, fw folded). NB=4: R16 behavior.
// Launcher picks via hipOccupancyMaxActiveBlocksPerMultiprocessor (host
// query, graph-safe): >=2 -> NB=2 grid 512; else NB=4 grid 256. This
// structurally excludes R8's serialized-rounds catastrophe.

#define B_    1024
#define T_    64
#define D_    128
#define H_    128
#define HOR_  24
#define ATT_  64
#define LOG2E 1.4426950408889634f
#define C127  (1.f/127.f)
// LOG2E / 17496 (Lagrange first-form normalization folded into exp2 arg)
#define KLAG  8.245856315e-05f

typedef float f32x4  __attribute__((ext_vector_type(4)));
typedef short bf16x8 __attribute__((ext_vector_type(8)));
typedef int   i32x4  __attribute__((ext_vector_type(4)));

#define MFMA16(a,b,c) __builtin_amdgcn_mfma_f32_16x16x32_bf16((a),(b),(c),0,0,0)
#define MFMAI8(a,b,c) __builtin_amdgcn_mfma_i32_16x16x64_i8((a),(b),(c),0,0,0)

// ---- workspace layout (same packing as R5..R16) ----
#define WHS_E    0        // base GEMM  B bf16: kt0..7, nt0..3  (16384 el)
#define WDDC_E   16384    // dc GEMM    B bf16: kt0..7, nt0..3  (16384 el)
#define WDENC_E  32768    // proj GEMM  B bf16: kt0..3, nt0..3  ( 8192 el)
#define WENC8_B  81920    // i8 enc gates B: [kt4][nt32][lane64][16] (131072 B)
#define WDEC8_B  212992   // i8 dec gates B: [kt2][nt32][lane64][16] ( 65536 B)
#define SENC_B   278528   // 512 f32 per-col scales (enc)
#define SDEC_B   280576   // 512 f32 per-col scales (dec)

__device__ __forceinline__ short f2b(float f) {        // fp32 -> bf16 RNE
  union { float f; unsigned u; } c; c.f = f;
  unsigned r = c.u + 0x7fffu + ((c.u >> 16) & 1u);
  return (short)(r >> 16);
}
__device__ __forceinline__ float b2f(short s) {
  union { unsigned u; float f; } c; c.u = ((unsigned)(unsigned short)s) << 16;
  return c.f;
}
__device__ __forceinline__ float fexp2(float x) { return __builtin_amdgcn_exp2f(x); }
__device__ __forceinline__ float frcp (float x) { return __builtin_amdgcn_rcpf(x); }
__device__ __forceinline__ float tanh_acc(float x) {   // 1 - 2/(1+e^{2x})
  float e = fexp2(x * 2.885390081777927f);
  return 1.f - 2.f * frcp(1.f + e);
}
__device__ __forceinline__ float sigm(float x) {
  return frcp(1.f + fexp2(-LOG2E * x));
}

// ---- fast cross-lane: DPP xor1/2/4/8, ds_swizzle xor16, shfl xor32 ----
template<int CTRL>
__device__ __forceinline__ float dppmov(float v) {
  return __builtin_bit_cast(float,
      __builtin_amdgcn_mov_dpp(__builtin_bit_cast(int, v), CTRL, 0xF, 0xF, true));
}
__device__ __forceinline__ float swz16(float v) {      // lane ^= 16
  return __builtin_bit_cast(float,
      __builtin_amdgcn_ds_swizzle(__builtin_bit_cast(int, v), 0x401F));
}
__device__ __forceinline__ float wsum64(float v) {
  v += dppmov<0xB1>(v);        // xor1  (quad_perm 1,0,3,2)
  v += dppmov<0x4E>(v);        // xor2  (quad_perm 2,3,0,1)
  v += dppmov<0x141>(v);       // xor4  (row_half_mirror)
  v += dppmov<0x140>(v);       // xor8  (row_mirror)
  v += swz16(v);               // xor16
  v += __shfl_xor(v, 32, 64);  // xor32 (permlane32_swap UNSAFE when aliased - R12)
  return v;
}
__device__ __forceinline__ float wmax64(float v) {
  v = fmaxf(v, dppmov<0xB1>(v));
  v = fmaxf(v, dppmov<0x4E>(v));
  v = fmaxf(v, dppmov<0x141>(v));
  v = fmaxf(v, dppmov<0x140>(v));
  v = fmaxf(v, swz16(v));
  v = fmaxf(v, __shfl_xor(v, 32, 64));
  return v;
}
__device__ __forceinline__ float gsum8(float v) {      // sum within group of 8
  v += dppmov<0xB1>(v);
  v += dppmov<0x4E>(v);
  v += dppmov<0x141>(v);
  return v;
}

// ---- prep1: bf16 B-frags (base / dc / proj), one element per thread ----
__global__ void prep_bf(const float* __restrict__ We_w,
                        const float* __restrict__ Wd_w,
                        char* __restrict__ ws8) {
  int e = blockIdx.x * 256 + threadIdx.x;
  if (e >= 40960) return;
  short* f16 = (short*)ws8;
  int region = e >> 14;                  // 0=WHS 1=WDDC 2=WDENC
  int er = e & 16383;
  int fi = er >> 9, li = (er >> 3) & 63, jq = er & 7;
  int kt = fi >> 2, nt = fi & 3;
  int k = kt * 32 + ((li >> 4) << 3) + jq, n = nt * 16 + (li & 15);
  float v;
  if (region == 0)      v = We_w[n * 257 + k];
  else if (region == 1) v = (k < 128) ? Wd_w[n * 384 + 128 + k]
                                      : Wd_w[n * 384 + 256 + (k - 128)];
  else                  v = Wd_w[n * 384 + k];
  f16[e] = f2b(v);
}

// ---- prep2: i8 quantized gates weights, one wave per column ----
__global__ void prep_q(const float* __restrict__ enc_Wih,
                       const float* __restrict__ enc_Whh,
                       const float* __restrict__ dec_Whh,
                       char* __restrict__ ws8) {
  int gw = (blockIdx.x * 256 + threadIdx.x) >> 6;
  int lane = threadIdx.x & 63;
  if (gw < 512) {                        // encoder col, K=256
    int n = gw;
    float v[4]; float m = 0.f;
#pragma unroll
    for (int q = 0; q < 4; ++q) {
      int k = lane * 4 + q;
      v[q] = (k < 128) ? enc_Wih[n * 128 + k] : enc_Whh[n * 128 + (k - 128)];
      m = fmaxf(m, fabsf(v[q]));
    }
    m = wmax64(m);
    if (lane == 0) ((float*)(ws8 + SENC_B))[n] = m * C127;
    float inv = m > 0.f ? 127.f / m : 0.f;
    char* dst = ws8 + WENC8_B;
#pragma unroll
    for (int q = 0; q < 4; ++q) {
      int k = lane * 4 + q;
      int kt = k >> 6, grp = (k >> 4) & 3, b = k & 15, l16 = (n & 15) | (grp << 4);
      dst[((kt * 32 + (n >> 4)) * 64 + l16) * 16 + b] = (char)(int)rintf(v[q] * inv);
    }
  } else if (gw < 1024) {                // decoder col, K=128
    int n = gw - 512;
    float v[2]; float m = 0.f;
#pragma unroll
    for (int q = 0; q < 2; ++q) {
      int k = lane * 2 + q;
      v[q] = dec_Whh[n * 128 + k];
      m = fmaxf(m, fabsf(v[q]));
    }
    m = wmax64(m);
    if (lane == 0) ((float*)(ws8 + SDEC_B))[n] = m * C127;
    float inv = m > 0.f ? 127.f / m : 0.f;
    char* dst = ws8 + WDEC8_B;
#pragma unroll
    for (int q = 0; q < 2; ++q) {
      int k = lane * 2 + q;
      int kt = k >> 6, grp = (k >> 4) & 3, b = k & 15, l16 = (n & 15) | (grp << 4);
      dst[((kt * 32 + (n >> 4)) * 64 + l16) * 16 + b] = (char)(int)rintf(v[q] * inv);
    }
  }
}

template<int NB>
__global__ __launch_bounds__(512, (NB == 2 ? 4 : 2))
void da_rnn_t(const float* __restrict__ X, const float* __restrict__ y_hist,
              const float* __restrict__ We_w, const float* __restrict__ We_b,
              const float* __restrict__ ve_w,
              const float* __restrict__ enc_bih, const float* __restrict__ enc_bhh,
              const float* __restrict__ dec_Wih,
              const float* __restrict__ dec_bih, const float* __restrict__ dec_bhh,
              const float* __restrict__ Wd_b, const float* __restrict__ vd_w,
              const float* __restrict__ fc_w, const float* __restrict__ fc_b,
              const char* __restrict__ ws8, float* __restrict__ out) {
  const short* f16  = (const short*)ws8;
  const i32x4* enc8 = (const i32x4*)(ws8 + WENC8_B);
  const i32x4* dec8 = (const i32x4*)(ws8 + WDEC8_B);
  const float* senc = (const float*)(ws8 + SENC_B);
  const float* sdec = (const float*)(ws8 + SDEC_B);

  // per-wave scratch geometry inside s_gates (enc P_GE transpose bounce)
  constexpr int SCR_PW = (NB == 4) ? 264 : 132;   // floats per wave
  constexpr int SCR_G  = (NB == 4) ? 64  : 32;    // gate stride

  // strides mod 32 words: s_A8 68=4, s_Ahc 132=4, s_gates 528=16, s_base 72=8
  __shared__ __align__(16) char  s_A8[16][272];   // gates A i8
  __shared__ __align__(16) short s_Ahc[16][264];  // base/dc/proj A bf16 [h;c]
  __shared__ short s_projT[NB][64][65];           // enc_proj^T
  __shared__ short s_encht[NB][128][66];          // enc_hiddens [r][j][t] bf16
  __shared__ __align__(16) float s_gates[NB][528];// dec gates / enc scratch
  __shared__ __align__(16) float s_base[NB][72];  // enc: base ; dec: dc
  __shared__ float s_beta[NB][64];
  __shared__ float s_xr[NB];
  __shared__ float2 s_wv[64];                     // (w_feat[k], ve_w[k])
  __shared__ __align__(16) float s_web[64];
  __shared__ float s_vd[64];
  __shared__ __align__(16) float s_wdb[64];
  __shared__ float s_se[512], s_sd[512];
  __shared__ float s_encb[512], s_decb[512], s_dwih[512];
  __shared__ float s_fcw[320];

  const int tid  = threadIdx.x;
  const int lane = tid & 63;
  const int w    = tid >> 6;        // wave 0..7 ; waves 0..NB-1 own row w
  const int b0   = blockIdx.x * NB;

  // ---- init ----
  if (tid < 64) {
    s_wv[tid]  = make_float2(We_w[tid * 257 + 256], ve_w[tid]);
    s_web[tid] = We_b[tid];
    s_vd[tid]  = vd_w[tid];
    s_wdb[tid] = Wd_b[tid];
  }
  if (tid < 320) s_fcw[tid] = fc_w[tid];
  s_se[tid]   = senc[tid];
  s_sd[tid]   = sdec[tid];
  s_encb[tid] = enc_bih[tid] + enc_bhh[tid];
  s_decb[tid] = dec_bih[tid] + dec_bhh[tid];
  s_dwih[tid] = dec_Wih[tid];
  for (int i = tid; i < (16 * 272) / 4; i += 512) ((int*)s_A8)[i] = 0;
  for (int i = tid; i < (16 * 264) / 2; i += 512) ((int*)s_Ahc)[i] = 0;
  if (tid < 64 * NB) s_base[tid >> 6][tid & 63] = We_b[tid & 63];  // base_0

  // ---- register-resident weights (loaded once, L2) ----
  i32x4 wg[4][4];                       // enc gates i8, nt = w + 8i
#pragma unroll
  for (int kt = 0; kt < 4; ++kt)
#pragma unroll
    for (int i = 0; i < 4; ++i)
      wg[kt][i] = enc8[(kt * 32 + (w + 8 * i)) * 64 + lane];
  bf16x8 wb[8], wp[4];
  if (w < 4) {
#pragma unroll
    for (int kt = 0; kt < 8; ++kt)
      wb[kt] = *(const bf16x8*)(f16 + WHS_E + ((kt * 4 + w) * 64 + lane) * 8);
  } else {
#pragma unroll
    for (int kt = 0; kt < 4; ++kt)
      wp[kt] = *(const bf16x8*)(f16 + WDENC_E + ((kt * 4 + (w - 4)) * 64 + lane) * 8);
  }

  // per-row attention state (waves 0..NB-1): features j0=lane, j1=lane+64
  float xf0 = 0.f, xf1 = 0.f, xi = 0.f;
  const float* Xr = X + (size_t)(b0 + (w & (NB - 1))) * T_ * D_;
  if (w < NB) {
    xf0 = Xr[lane]; xf1 = Xr[64 + lane];    // x(t=0), consumed top of P_A(0)
    xi = 6.f * cosf((2 * (lane >> 3) + 1) * 0.19634954084936207f);  // node
  }
  // merged-epilogue cell: wave w owns features 16w..16w+15 x rows 0..NB-1
  float cM = 0.f;
  const int bM   = lane >> 4;
  const int phil = lane & 15;
  const int phig = (w << 4) + phil;
  // h-side gates contribution (precomputed each P_B; h_0 = 0 -> zero)
  i32x4 ahp[4];
#pragma unroll
  for (int i = 0; i < 4; ++i) ahp[i] = (i32x4){0, 0, 0, 0};
  __syncthreads();

  // ---- per-wave preloads (post-barrier: LDS constants now valid) ----
  float seM[4], ebM[4];
#pragma unroll
  for (int q = 0; q < 4; ++q) {
    seM[q] = s_se[q * 128 + phig];
    ebM[q] = s_encb[q * 128 + phig];
  }
  f32x4 webq = {0.f, 0.f, 0.f, 0.f};
  if (w < 4) webq = *(const f32x4*)&s_web[(w << 4) + ((lane >> 4) << 2)];

  // ====================== encoder ======================
  for (int t = 0; t < T_; ++t) {
    // ---- P_A: attention (w<NB, prio) | proj_{t-1} (w4-7) ----
    float x0, x1;
    if (w < NB) {
      __builtin_amdgcn_s_setprio(1);
      x0 = xf0; x1 = xf1;                 // prefetched one step ago
      const int kc = lane & 7;
      float p = 0.f;
      const float4* wvp = (const float4*)&s_wv[kc * 8];
      const float4* bp  = (const float4*)&s_base[w][kc * 8];
      float4 bA = bp[0], bB = bp[1];
#pragma unroll
      for (int q = 0; q < 4; ++q) {
        float4 wv = wvp[q];                       // (w_k, ve_k, w_{k+1}, ve_{k+1})
        float bb0 = (q < 2) ? ((q & 1) ? bA.z : bA.x) : ((q & 1) ? bB.z : bB.x);
        float bb1 = (q < 2) ? ((q & 1) ? bA.w : bA.y) : ((q & 1) ? bB.w : bB.y);
        p += wv.y * tanh_acc(fmaf(xi, wv.x, bb0));
        p += wv.w * tanh_acc(fmaf(xi, wv.z, bb1));
      }
      p = gsum8(p);                               // sum over kc within node grp
      float fv0 = __shfl(p,  0, 64), fv1 = __shfl(p,  8, 64);
      float fv2 = __shfl(p, 16, 64), fv3 = __shfl(p, 24, 64);
      float fv4 = __shfl(p, 32, 64), fv5 = __shfl(p, 40, 64);
      float fv6 = __shfl(p, 48, 64), fv7 = __shfl(p, 56, 64);
      // Lagrange FIRST form at u = clamp(x,+-6): rcp-free, d recomputed
      // (register diet: no d/fw arrays; f*(wbar*P) association)
      float e0, e1;
      {
        const float xb[8] = { 5.884711682f, 4.988817674f, 3.333421398f, 1.170541932f,
                             -1.170541932f, -3.333421398f, -4.988817674f, -5.884711682f};
        const float wbar[8] = { 0.1950903220f, -0.5555702330f, 0.8314696123f, -0.9807852804f,
                                0.9807852804f, -0.8314696123f, 0.5555702330f, -0.1950903220f};
        float fvv[8] = {fv0, fv1, fv2, fv3, fv4, fv5, fv6, fv7};
        float u0 = fminf(fmaxf(x0, -6.f), 6.f), u1 = fminf(fmaxf(x1, -6.f), 6.f);
        float P0[8], P1[8];
        float pre0 = 1.f, pre1 = 1.f;
#pragma unroll
        for (int i = 0; i < 8; ++i) {
          P0[i] = pre0;            P1[i] = pre1;
          pre0 *= (u0 - xb[i]);    pre1 *= (u1 - xb[i]);
        }
        float suf0 = 1.f, suf1 = 1.f, acc0 = 0.f, acc1 = 0.f;
#pragma unroll
        for (int i = 7; i >= 0; --i) {
          acc0 = fmaf(fvv[i] * (wbar[i] * P0[i]), suf0, acc0);
          acc1 = fmaf(fvv[i] * (wbar[i] * P1[i]), suf1, acc1);
          suf0 *= (u0 - xb[i]);
          suf1 *= (u1 - xb[i]);
        }
        e0 = fexp2(acc0 * KLAG);                  // exp(sc), sc=acc/17496
        e1 = fexp2(acc1 * KLAG);
      }
      float sum = wsum64(e0 + e1);
      float mx  = wmax64(fmaxf(e0 * fabsf(x0), e1 * fabsf(x1)));
      float inv = mx > 0.f ? 127.f * frcp(mx) : 0.f;
      s_A8[w][lane]      = (char)(int)rintf(x0 * e0 * inv);
      s_A8[w][64 + lane] = (char)(int)rintf(x1 * e1 * inv);
      if (lane == 0) s_xr[w] = mx * frcp(127.f * sum);
      __builtin_amdgcn_s_setprio(0);
    } else if (w >= 4 && t > 0) {
      f32x4 acc = {0.f, 0.f, 0.f, 0.f};
#pragma unroll
      for (int kt = 0; kt < 4; ++kt) {
        bf16x8 a = *(const bf16x8*)&s_Ahc[lane & 15][kt * 32 + ((lane >> 4) << 3)];
        acc = MFMA16(a, wp[kt], acc);    // original orientation (strided store)
      }
      if (lane < 16) {
        int katt = (w - 4) * 16 + lane;
#pragma unroll
        for (int r = 0; r < NB; ++r) s_projT[r][katt][t - 1] = f2b(acc[r]);
      }
    }
    __syncthreads();                                            // B1
    // ---- P_GE: gates i8 GEMM (C^T) + in-wave transpose + fused epilogue ----
    {
      i32x4 a0 = *(const i32x4*)&s_A8[lane & 15][  0 + ((lane >> 4) << 4)];
      i32x4 a1 = *(const i32x4*)&s_A8[lane & 15][ 64 + ((lane >> 4) << 4)];
      i32x4 ax[4];
#pragma unroll
      for (int i = 0; i < 4; ++i) {
        i32x4 z = {0, 0, 0, 0};
        ax[i] = MFMAI8(wg[1][i], a1, MFMAI8(wg[0][i], a0, z));
      }
      float* scr = ((float*)s_gates) + w * SCR_PW;   // per-wave scratch
      float sx = s_xr[lane & (NB - 1)];
      if ((lane & 15) < NB) {
        int off = ((lane & 15) << 4) + ((lane >> 4) << 2);  // brow*16 + col
#pragma unroll
        for (int i = 0; i < 4; ++i) {
          f32x4 v;
#pragma unroll
          for (int r = 0; r < 4; ++r)
            v[r] = fmaf(sx, (float)ax[i][r], C127 * (float)ahp[i][r]);
          *(f32x4*)&scr[i * SCR_G + off] = v;
        }
      }
      asm volatile("" ::: "memory");  // keep write->read program order
      if (bM < NB) {
        int ra = (bM << 4) + phil;
        float g_i = fmaf(scr[0 * SCR_G + ra], seM[0], ebM[0]);
        float g_f = fmaf(scr[1 * SCR_G + ra], seM[1], ebM[1]);
        float g_g = fmaf(scr[2 * SCR_G + ra], seM[2], ebM[2]);
        float g_o = fmaf(scr[3 * SCR_G + ra], seM[3], ebM[3]);
        cM = sigm(g_f) * cM + sigm(g_i) * tanh_acc(g_g);
        float h = sigm(g_o) * tanh_acc(cM);
        s_Ahc[bM][phig]       = f2b(h);
        s_Ahc[bM][128 + phig] = f2b(cM);
        s_A8[bM][128 + phig]  = (char)(int)rintf(h * 127.f);
        s_encht[bM][phig][t]  = f2b(h);
      }
    }
    __syncthreads();                                            // B2
    // ---- P_B: base_{t+1} (w0-3, transposed) ; ah-precompute (all waves) ----
    {
      i32x4 pa2 = *(const i32x4*)&s_A8[lane & 15][128 + ((lane >> 4) << 4)];
      i32x4 pa3 = *(const i32x4*)&s_A8[lane & 15][192 + ((lane >> 4) << 4)];
#pragma unroll
      for (int i = 0; i < 4; ++i) {
        i32x4 z = {0, 0, 0, 0};
        ahp[i] = MFMAI8(wg[3][i], pa3, MFMAI8(wg[2][i], pa2, z));
      }
    }
    if (w < NB && t < T_ - 1) {           // X prefetch: one full step early
      xf0 = Xr[(t + 1) * D_ + lane];
      xf1 = Xr[(t + 1) * D_ + 64 + lane];
    }
    if (w < 4) {
      f32x4 acc = {0.f, 0.f, 0.f, 0.f}, acc2 = {0.f, 0.f, 0.f, 0.f};
#pragma unroll
      for (int kt = 0; kt < 4; ++kt) {
        bf16x8 a = *(const bf16x8*)&s_Ahc[lane & 15][kt * 32 + ((lane >> 4) << 3)];
        acc = MFMA16(wb[kt], a, acc);
      }
#pragma unroll
      for (int kt = 4; kt < 8; ++kt) {
        bf16x8 a = *(const bf16x8*)&s_Ahc[lane & 15][kt * 32 + ((lane >> 4) << 3)];
        acc2 = MFMA16(wb[kt], a, acc2);
      }
      if ((lane & 15) < NB) {
        f32x4 v = acc + acc2 + webq;
        *(f32x4*)&s_base[lane & 15][(w << 4) + ((lane >> 4) << 2)] = v;
      }
    }
    __syncthreads();                                            // B3
  }
  // ---- final proj(T-1) (w4-7; s_Ahc still holds [h;c]_{T-1}) ----
  if (w >= 4) {
    f32x4 acc = {0.f, 0.f, 0.f, 0.f};
#pragma unroll
    for (int kt = 0; kt < 4; ++kt) {
      bf16x8 a = *(const bf16x8*)&s_Ahc[lane & 15][kt * 32 + ((lane >> 4) << 3)];
      acc = MFMA16(a, wp[kt], acc);
    }
    if (lane < 16) {
      int katt = (w - 4) * 16 + lane;
#pragma unroll
      for (int r = 0; r < NB; ++r) s_projT[r][katt][T_ - 1] = f2b(acc[r]);
    }
  }
  __syncthreads();

  // ====================== decoder ======================
  {
    int r = tid >> 7, j = tid & 127;
    if (r < NB) { s_Ahc[r][j] = 0; s_Ahc[r][128 + j] = 0; s_A8[r][j] = 0; }
  }
  i32x4 wdg[2][8];                      // dec gates i8 (waves 4-7), nt=(w-4)*8+i
  bf16x8 wdc[8];                        // dc bf16 (waves 0-3)
  float yp = 0.f, yhd = 0.f;
  float sdC_p[8], db_p[8], dw_p[8];
  f32x4 wdbq = {0.f, 0.f, 0.f, 0.f};
  if (w >= 4) {
#pragma unroll
    for (int kt = 0; kt < 2; ++kt)
#pragma unroll
      for (int i = 0; i < 8; ++i)
        wdg[kt][i] = dec8[(kt * 32 + ((w - 4) * 8 + i)) * 64 + lane];
  } else {
#pragma unroll
    for (int kt = 0; kt < 8; ++kt)
      wdc[kt] = *(const bf16x8*)(f16 + WDDC_E + ((kt * 4 + w) * 64 + lane) * 8);
    wdbq = *(const f32x4*)&s_wdb[(w << 4) + ((lane >> 4) << 2)];
    if (w < NB) {
#pragma unroll
      for (int j = 0; j < 8; ++j) {
        sdC_p[j] = s_sd[lane + 64 * j] * C127;
        db_p[j]  = s_decb[lane + 64 * j];
        dw_p[j]  = s_dwih[lane + 64 * j];
      }
      yp = y_hist[(b0 + w) * T_ + (T_ - 1)];
      float pp = s_fcw[256 + lane] * y_hist[(b0 + w) * T_ + lane];
      yhd = wsum64(pp) + fc_b[0];
    }
  }
  float dd0 = 0.f, dc0 = 0.f, dd1 = 0.f, dc1 = 0.f;   // d, cc (2 feats/lane)
  __syncthreads();

  for (int hs = 0; hs < HOR_; ++hs) {
    // ---- Phase A: w<NB {context+fc+out(hs-1)}, w0-3 {dc GEMM} | w4-7 {gates}
    if (w >= 4) {
      i32x4 a0 = *(const i32x4*)&s_A8[lane & 15][ 0 + ((lane >> 4) << 4)];
      i32x4 a1 = *(const i32x4*)&s_A8[lane & 15][64 + ((lane >> 4) << 4)];
#pragma unroll
      for (int i = 0; i < 8; ++i) {
        i32x4 z = {0, 0, 0, 0};
        i32x4 ac = MFMAI8(wdg[1][i], a1, MFMAI8(wdg[0][i], a0, z));
        if ((lane & 15) < NB) {
          f32x4 v = {(float)ac[0], (float)ac[1], (float)ac[2], (float)ac[3]};
          *(f32x4*)&s_gates[lane & 15][(((w - 4) * 8 + i) << 4) + ((lane >> 4) << 2)] = v;
        }
      }
    } else {
      if (hs > 0 && w < NB) {
        // context for step hs-1 (beta from last Phase B) + fc + out
        float cx0a = 0.f, cx0b = 0.f, cx1a = 0.f, cx1b = 0.f;
        const short* e0p = &s_encht[w][lane][0];
        const short* e1p = &s_encht[w][lane + 64][0];
#pragma unroll 8
        for (int tp = 0; tp < 32; ++tp) {
          float2 bta = *(const float2*)&s_beta[w][2 * tp];
          short2 h0v = *(const short2*)&e0p[2 * tp];
          short2 h1v = *(const short2*)&e1p[2 * tp];
          cx0a = fmaf(bta.x, b2f(h0v.x), cx0a); cx0b = fmaf(bta.y, b2f(h0v.y), cx0b);
          cx1a = fmaf(bta.x, b2f(h1v.x), cx1a); cx1b = fmaf(bta.y, b2f(h1v.y), cx1b);
        }
        float cx0 = cx0a + cx0b, cx1 = cx1a + cx1b;
        float pf = s_fcw[lane] * dd0 + s_fcw[64 + lane] * dd1
                 + s_fcw[128 + lane] * cx0 + s_fcw[192 + lane] * cx1;
        pf = wsum64(pf);
        float o = pf + yhd;
        if (lane == 0) out[(b0 + w) * HOR_ + (hs - 1)] = o;
        yp = o;
      }
      // dc GEMM (reads s_Ahc = d_hs written last Phase B)
      f32x4 acc = {0.f, 0.f, 0.f, 0.f}, acc2 = {0.f, 0.f, 0.f, 0.f};
#pragma unroll
      for (int kt = 0; kt < 4; ++kt) {
        bf16x8 a = *(const bf16x8*)&s_Ahc[lane & 15][kt * 32 + ((lane >> 4) << 3)];
        acc = MFMA16(wdc[kt], a, acc);
      }
#pragma unroll
      for (int kt = 4; kt < 8; ++kt) {
        bf16x8 a = *(const bf16x8*)&s_Ahc[lane & 15][kt * 32 + ((lane >> 4) << 3)];
        acc2 = MFMA16(wdc[kt], a, acc2);
      }
      if ((lane & 15) < NB) {
        f32x4 v = acc + acc2 + wdbq;
        *(f32x4*)&s_base[lane & 15][(w << 4) + ((lane >> 4) << 2)] = v;
      }
    }
    __syncthreads();                                            // B1
    // ---- Phase B: w<NB {LSTM epilogue} | w4..4+NB-1 {scores+softmax, prio}
    if (w < NB) {
      float gi0 = s_gates[w][lane]       * sdC_p[0] + db_p[0] + yp * dw_p[0];
      float gi1 = s_gates[w][lane + 64]  * sdC_p[1] + db_p[1] + yp * dw_p[1];
      float gf0 = s_gates[w][lane + 128] * sdC_p[2] + db_p[2] + yp * dw_p[2];
      float gf1 = s_gates[w][lane + 192] * sdC_p[3] + db_p[3] + yp * dw_p[3];
      float gg0 = s_gates[w][lane + 256] * sdC_p[4] + db_p[4] + yp * dw_p[4];
      float gg1 = s_gates[w][lane + 320] * sdC_p[5] + db_p[5] + yp * dw_p[5];
      float go0 = s_gates[w][lane + 384] * sdC_p[6] + db_p[6] + yp * dw_p[6];
      float go1 = s_gates[w][lane + 448] * sdC_p[7] + db_p[7] + yp * dw_p[7];
      dc0 = sigm(gf0) * dc0 + sigm(gi0) * tanh_acc(gg0);
      dd0 = sigm(go0) * tanh_acc(dc0);
      dc1 = sigm(gf1) * dc1 + sigm(gi1) * tanh_acc(gg1);
      dd1 = sigm(go1) * tanh_acc(dc1);
      // state for next Phase A GEMMs
      s_Ahc[w][lane]       = f2b(dd0);
      s_Ahc[w][lane + 64]  = f2b(dd1);
      s_Ahc[w][lane + 128] = f2b(dc0);
      s_Ahc[w][lane + 192] = f2b(dc1);
      s_A8[w][lane]      = (char)(int)rintf(dd0 * 127.f);
      s_A8[w][lane + 64] = (char)(int)rintf(dd1 * 127.f);
    } else if (w >= 4 && (w - 4) < NB) {
      __builtin_amdgcn_s_setprio(1);
      const int r = w - 4;
      float sA = 0.f, sB = 0.f, sC = 0.f, sD = 0.f;
#pragma unroll 4
      for (int k = 0; k < 64; k += 4) {
        sA += s_vd[k]     * tanh_acc(b2f(s_projT[r][k][lane])     + s_base[r][k]);
        sB += s_vd[k + 1] * tanh_acc(b2f(s_projT[r][k + 1][lane]) + s_base[r][k + 1]);
        sC += s_vd[k + 2] * tanh_acc(b2f(s_projT[r][k + 2][lane]) + s_base[r][k + 2]);
        sD += s_vd[k + 3] * tanh_acc(b2f(s_projT[r][k + 3][lane]) + s_base[r][k + 3]);
      }
      float s = (sA + sB) + (sC + sD);
      float e = fexp2(s * LOG2E);
      float ssum = wsum64(e);
      s_beta[r][lane] = e * frcp(ssum);
      __builtin_amdgcn_s_setprio(0);
    }
    __syncthreads();                                            // B2
  }
  // ---- tail: final context+fc+out for hs = HOR_-1 (w<NB) ----
  if (w < NB) {
    float cx0a = 0.f, cx0b = 0.f, cx1a = 0.f, cx1b = 0.f;
    const short* e0p = &s_encht[w][lane][0];
    const short* e1p = &s_encht[w][lane + 64][0];
#pragma unroll 8
    for (int tp = 0; tp < 32; ++tp) {
      float2 bta = *(const float2*)&s_beta[w][2 * tp];
      short2 h0v = *(const short2*)&e0p[2 * tp];
      short2 h1v = *(const short2*)&e1p[2 * tp];
      cx0a = fmaf(bta.x, b2f(h0v.x), cx0a); cx0b = fmaf(bta.y, b2f(h0v.y), cx0b);
      cx1a = fmaf(bta.x, b2f(h1v.x), cx1a); cx1b = fmaf(bta.y, b2f(h1v.y), cx1b);
    }
    float cx0 = cx0a + cx0b, cx1 = cx1a + cx1b;
    float pf = s_fcw[lane] * dd0 + s_fcw[64 + lane] * dd1
             + s_fcw[128 + lane] * cx0 + s_fcw[192 + lane] * cx1;
    pf = wsum64(pf);
    float o = pf + yhd;
    if (lane == 0) out[(b0 + w) * HOR_ + (HOR_ - 1)] = o;
  }
}

extern "C" void kernel_launch(void* const* d_in, const int* in_sizes, int n_in,
                              void* d_out, int out_size, void* d_ws, size_t ws_size,
                              hipStream_t stream) {
  (void)in_sizes; (void)n_in; (void)out_size; (void)ws_size;
  const float* X       = (const float*)d_in[0];
  const float* y_hist  = (const float*)d_in[1];
  const float* We_w    = (const float*)d_in[2];
  const float* We_b    = (const float*)d_in[3];
  const float* ve_w    = (const float*)d_in[4];
  // d_in[5] = ve_b : softmax-invariant, unused
  const float* enc_Wih = (const float*)d_in[6];
  const float* enc_Whh = (const float*)d_in[7];
  const float* enc_bih = (const float*)d_in[8];
  const float* enc_bhh = (const float*)d_in[9];
  const float* dec_Wih = (const float*)d_in[10];
  const float* dec_Whh = (const float*)d_in[11];
  const float* dec_bih = (const float*)d_in[12];
  const float* dec_bhh = (const float*)d_in[13];
  const float* Wd_w    = (const float*)d_in[14];
  const float* Wd_b    = (const float*)d_in[15];
  const float* vd_w    = (const float*)d_in[16];
  // d_in[17] = vd_b : softmax-invariant, unused
  const float* fc_w    = (const float*)d_in[18];
  const float* fc_b    = (const float*)d_in[19];

  char* ws8  = (char*)d_ws;
  float* out = (float*)d_out;

  prep_bf<<<160, 256, 0, stream>>>(We_w, Wd_w, ws8);
  prep_q <<<256, 256, 0, stream>>>(enc_Wih, enc_Whh, dec_Whh, ws8);

  // occupancy-gated dispatch: BB=2 only if 2 blocks/CU actually fit
  // (grid 512 with 1 block/CU would SERIALIZE two full chain rounds - R8)
  int nb2 = 0;
  (void)hipOccupancyMaxActiveBlocksPerMultiprocessor(
      &nb2, reinterpret_cast<const void*>(&da_rnn_t<2>), 512, 0);
  if (nb2 >= 2) {
    da_rnn_t<2><<<B_ / 2, 512, 0, stream>>>(X, y_hist, We_w, We_b, ve_w,
                                            enc_bih, enc_bhh, dec_Wih, dec_bih,
                                            dec_bhh, Wd_b, vd_w, fc_w, fc_b,
                                            ws8, out);
  } else {
    da_rnn_t<4><<<B_ / 4, 512, 0, stream>>>(X, y_hist, We_w, We_b, ve_w,
                                            enc_bih, enc_bhh, dec_Wih, dec_bih,
                                            dec_bhh, Wd_b, vd_w, fc_w, fc_b,
                                            ws8, out);
  }
}

// Round 12
// 291.380 us; speedup vs baseline: 1.0182x; 1.0182x over previous
//
#include <hip/hip_runtime.h>
#include <hip/hip_bf16.h>

// DA-RNN persistent kernel, round 18: revert R17, restore R16 + readlane.
// R17 post-mortem: the occupancy gate is BLIND TO SPILL — the compiler made
// NB=2 "fit" 4 blocks/CU by compiling at 64 arch VGPRs (spilling): FETCH
// 1.6GB, WRITE 185MB, 296us. Register-resident weights (wg=64 VGPRs +
// wb/wp/wdg/wdc=32 + state) are irreducibly >128-total -> co-residency is
// structurally infeasible (R7, R8, R17 bound it from all sides: CLOSED).
// R18 = R16 verbatim (proven 204us) + one chain shortener: the 8
// __shfl(p, 8i) broadcasts in P_A become v_readlane_b32 (p is
// group-uniform after gsum8; readlane is VALU-speed, no DS pipe, exec-
// independent and all relevant lanes are active). Identical bits -> absmax
// unchanged.
// BB=4, 256 blocks, __launch_bounds__(512,2): proven no-spill regime.

#define B_    1024
#define T_    64
#define D_    128
#define H_    128
#define HOR_  24
#define ATT_  64
#define BB    4
#define LOG2E 1.4426950408889634f
#define C127  (1.f/127.f)
// LOG2E / 17496 (Lagrange first-form normalization folded into exp2 arg)
#define KLAG  8.245856315e-05f

typedef float f32x4  __attribute__((ext_vector_type(4)));
typedef short bf16x8 __attribute__((ext_vector_type(8)));
typedef int   i32x4  __attribute__((ext_vector_type(4)));

#define MFMA16(a,b,c) __builtin_amdgcn_mfma_f32_16x16x32_bf16((a),(b),(c),0,0,0)
#define MFMAI8(a,b,c) __builtin_amdgcn_mfma_i32_16x16x64_i8((a),(b),(c),0,0,0)

// ---- workspace layout (same packing as R5..R16) ----
#define WHS_E    0        // base GEMM  B bf16: kt0..7, nt0..3  (16384 el)
#define WDDC_E   16384    // dc GEMM    B bf16: kt0..7, nt0..3  (16384 el)
#define WDENC_E  32768    // proj GEMM  B bf16: kt0..3, nt0..3  ( 8192 el)
#define WENC8_B  81920    // i8 enc gates B: [kt4][nt32][lane64][16] (131072 B)
#define WDEC8_B  212992   // i8 dec gates B: [kt2][nt32][lane64][16] ( 65536 B)
#define SENC_B   278528   // 512 f32 per-col scales (enc)
#define SDEC_B   280576   // 512 f32 per-col scales (dec)

__device__ __forceinline__ short f2b(float f) {        // fp32 -> bf16 RNE
  union { float f; unsigned u; } c; c.f = f;
  unsigned r = c.u + 0x7fffu + ((c.u >> 16) & 1u);
  return (short)(r >> 16);
}
__device__ __forceinline__ float b2f(short s) {
  union { unsigned u; float f; } c; c.u = ((unsigned)(unsigned short)s) << 16;
  return c.f;
}
__device__ __forceinline__ float fexp2(float x) { return __builtin_amdgcn_exp2f(x); }
__device__ __forceinline__ float frcp (float x) { return __builtin_amdgcn_rcpf(x); }
__device__ __forceinline__ float tanh_acc(float x) {   // 1 - 2/(1+e^{2x})
  float e = fexp2(x * 2.885390081777927f);
  return 1.f - 2.f * frcp(1.f + e);
}
__device__ __forceinline__ float sigm(float x) {
  return frcp(1.f + fexp2(-LOG2E * x));
}

// ---- fast cross-lane: DPP xor1/2/4/8, ds_swizzle xor16, shfl xor32 ----
template<int CTRL>
__device__ __forceinline__ float dppmov(float v) {
  return __builtin_bit_cast(float,
      __builtin_amdgcn_mov_dpp(__builtin_bit_cast(int, v), CTRL, 0xF, 0xF, true));
}
__device__ __forceinline__ float swz16(float v) {      // lane ^= 16
  return __builtin_bit_cast(float,
      __builtin_amdgcn_ds_swizzle(__builtin_bit_cast(int, v), 0x401F));
}
__device__ __forceinline__ float rdlane(float v, int l) {  // wave-uniform read
  return __builtin_bit_cast(float,
      __builtin_amdgcn_readlane(__builtin_bit_cast(int, v), l));
}
__device__ __forceinline__ float wsum64(float v) {
  v += dppmov<0xB1>(v);        // xor1  (quad_perm 1,0,3,2)
  v += dppmov<0x4E>(v);        // xor2  (quad_perm 2,3,0,1)
  v += dppmov<0x141>(v);       // xor4  (row_half_mirror)
  v += dppmov<0x140>(v);       // xor8  (row_mirror)
  v += swz16(v);               // xor16
  v += __shfl_xor(v, 32, 64);  // xor32 (permlane32_swap UNSAFE when aliased - R12)
  return v;
}
__device__ __forceinline__ float wmax64(float v) {
  v = fmaxf(v, dppmov<0xB1>(v));
  v = fmaxf(v, dppmov<0x4E>(v));
  v = fmaxf(v, dppmov<0x141>(v));
  v = fmaxf(v, dppmov<0x140>(v));
  v = fmaxf(v, swz16(v));
  v = fmaxf(v, __shfl_xor(v, 32, 64));
  return v;
}
__device__ __forceinline__ float gsum8(float v) {      // sum within group of 8
  v += dppmov<0xB1>(v);
  v += dppmov<0x4E>(v);
  v += dppmov<0x141>(v);
  return v;
}

// ---- prep1: bf16 B-frags (base / dc / proj), one element per thread ----
__global__ void prep_bf(const float* __restrict__ We_w,
                        const float* __restrict__ Wd_w,
                        char* __restrict__ ws8) {
  int e = blockIdx.x * 256 + threadIdx.x;
  if (e >= 40960) return;
  short* f16 = (short*)ws8;
  int region = e >> 14;                  // 0=WHS 1=WDDC 2=WDENC
  int er = e & 16383;
  int fi = er >> 9, li = (er >> 3) & 63, jq = er & 7;
  int kt = fi >> 2, nt = fi & 3;
  int k = kt * 32 + ((li >> 4) << 3) + jq, n = nt * 16 + (li & 15);
  float v;
  if (region == 0)      v = We_w[n * 257 + k];
  else if (region == 1) v = (k < 128) ? Wd_w[n * 384 + 128 + k]
                                      : Wd_w[n * 384 + 256 + (k - 128)];
  else                  v = Wd_w[n * 384 + k];
  f16[e] = f2b(v);
}

// ---- prep2: i8 quantized gates weights, one wave per column ----
__global__ void prep_q(const float* __restrict__ enc_Wih,
                       const float* __restrict__ enc_Whh,
                       const float* __restrict__ dec_Whh,
                       char* __restrict__ ws8) {
  int gw = (blockIdx.x * 256 + threadIdx.x) >> 6;
  int lane = threadIdx.x & 63;
  if (gw < 512) {                        // encoder col, K=256
    int n = gw;
    float v[4]; float m = 0.f;
#pragma unroll
    for (int q = 0; q < 4; ++q) {
      int k = lane * 4 + q;
      v[q] = (k < 128) ? enc_Wih[n * 128 + k] : enc_Whh[n * 128 + (k - 128)];
      m = fmaxf(m, fabsf(v[q]));
    }
    m = wmax64(m);
    if (lane == 0) ((float*)(ws8 + SENC_B))[n] = m * C127;
    float inv = m > 0.f ? 127.f / m : 0.f;
    char* dst = ws8 + WENC8_B;
#pragma unroll
    for (int q = 0; q < 4; ++q) {
      int k = lane * 4 + q;
      int kt = k >> 6, grp = (k >> 4) & 3, b = k & 15, l16 = (n & 15) | (grp << 4);
      dst[((kt * 32 + (n >> 4)) * 64 + l16) * 16 + b] = (char)(int)rintf(v[q] * inv);
    }
  } else if (gw < 1024) {                // decoder col, K=128
    int n = gw - 512;
    float v[2]; float m = 0.f;
#pragma unroll
    for (int q = 0; q < 2; ++q) {
      int k = lane * 2 + q;
      v[q] = dec_Whh[n * 128 + k];
      m = fmaxf(m, fabsf(v[q]));
    }
    m = wmax64(m);
    if (lane == 0) ((float*)(ws8 + SDEC_B))[n] = m * C127;
    float inv = m > 0.f ? 127.f / m : 0.f;
    char* dst = ws8 + WDEC8_B;
#pragma unroll
    for (int q = 0; q < 2; ++q) {
      int k = lane * 2 + q;
      int kt = k >> 6, grp = (k >> 4) & 3, b = k & 15, l16 = (n & 15) | (grp << 4);
      dst[((kt * 32 + (n >> 4)) * 64 + l16) * 16 + b] = (char)(int)rintf(v[q] * inv);
    }
  }
}

__global__ __launch_bounds__(512, 2)
void da_rnn(const float* __restrict__ X, const float* __restrict__ y_hist,
            const float* __restrict__ We_w, const float* __restrict__ We_b,
            const float* __restrict__ ve_w,
            const float* __restrict__ enc_bih, const float* __restrict__ enc_bhh,
            const float* __restrict__ dec_Wih,
            const float* __restrict__ dec_bih, const float* __restrict__ dec_bhh,
            const float* __restrict__ Wd_b, const float* __restrict__ vd_w,
            const float* __restrict__ fc_w, const float* __restrict__ fc_b,
            const char* __restrict__ ws8, float* __restrict__ out) {
  const short* f16  = (const short*)ws8;
  const i32x4* enc8 = (const i32x4*)(ws8 + WENC8_B);
  const i32x4* dec8 = (const i32x4*)(ws8 + WDEC8_B);
  const float* senc = (const float*)(ws8 + SENC_B);
  const float* sdec = (const float*)(ws8 + SDEC_B);

  // strides mod 32 words: s_A8 68=4, s_Ahc 132=4, s_gates 528=16, s_base 72=8
  __shared__ __align__(16) char  s_A8[16][272];   // gates A i8
  __shared__ __align__(16) short s_Ahc[16][264];  // base/dc/proj A bf16 [h;c]
  __shared__ short s_projT[4][64][65];            // enc_proj^T
  __shared__ short s_encht[4][128][66];           // enc_hiddens [r][j][t] bf16
  __shared__ __align__(16) float s_gates[4][528]; // dec gates / enc per-wave scratch
  __shared__ __align__(16) float s_base[4][72];   // enc: base ; dec: dc
  __shared__ float s_beta[4][64];
  __shared__ float s_xr[4];
  __shared__ float2 s_wv[64];                     // (w_feat[k], ve_w[k])
  __shared__ __align__(16) float s_web[64];
  __shared__ float s_vd[64];
  __shared__ __align__(16) float s_wdb[64];
  __shared__ float s_se[512], s_sd[512];
  __shared__ float s_encb[512], s_decb[512], s_dwih[512];
  __shared__ float s_fcw[320];

  const int tid  = threadIdx.x;
  const int lane = tid & 63;
  const int w    = tid >> 6;        // wave 0..7 ; waves 0-3 own row w
  const int b0   = blockIdx.x * BB;

  // ---- init ----
  if (tid < 64) {
    s_wv[tid]  = make_float2(We_w[tid * 257 + 256], ve_w[tid]);
    s_web[tid] = We_b[tid];
    s_vd[tid]  = vd_w[tid];
    s_wdb[tid] = Wd_b[tid];
  }
  if (tid < 320) s_fcw[tid] = fc_w[tid];
  s_se[tid]   = senc[tid];
  s_sd[tid]   = sdec[tid];
  s_encb[tid] = enc_bih[tid] + enc_bhh[tid];
  s_decb[tid] = dec_bih[tid] + dec_bhh[tid];
  s_dwih[tid] = dec_Wih[tid];
  for (int i = tid; i < (16 * 272) / 4; i += 512) ((int*)s_A8)[i] = 0;
  for (int i = tid; i < (16 * 264) / 2; i += 512) ((int*)s_Ahc)[i] = 0;
  if (tid < 256) s_base[tid >> 6][tid & 63] = We_b[tid & 63];  // base_0

  // ---- register-resident weights (loaded once, L2) ----
  i32x4 wg[4][4];                       // enc gates i8, nt = w + 8i
#pragma unroll
  for (int kt = 0; kt < 4; ++kt)
#pragma unroll
    for (int i = 0; i < 4; ++i)
      wg[kt][i] = enc8[(kt * 32 + (w + 8 * i)) * 64 + lane];
  bf16x8 wb[8], wp[4];
  if (w < 4) {
#pragma unroll
    for (int kt = 0; kt < 8; ++kt)
      wb[kt] = *(const bf16x8*)(f16 + WHS_E + ((kt * 4 + w) * 64 + lane) * 8);
  } else {
#pragma unroll
    for (int kt = 0; kt < 4; ++kt)
      wp[kt] = *(const bf16x8*)(f16 + WDENC_E + ((kt * 4 + (w - 4)) * 64 + lane) * 8);
  }

  // per-row attention state (waves 0-3): features j0=lane, j1=lane+64
  float xf0 = 0.f, xf1 = 0.f, xi = 0.f;
  const float* Xr = X + (size_t)(b0 + (w & 3)) * T_ * D_;
  if (w < 4) {
    xf0 = Xr[lane]; xf1 = Xr[64 + lane];    // x(t=0), consumed top of P_A(0)
    xi = 6.f * cosf((2 * (lane >> 3) + 1) * 0.19634954084936207f);  // node
  }
  // merged-epilogue cell: wave w owns features 16w..16w+15 x rows 0..3
  //   cell = (row bM = lane>>4, feature phig = 16w + (lane&15))
  float cM = 0.f;
  const int bM   = lane >> 4;
  const int phil = lane & 15;
  const int phig = (w << 4) + phil;
  // h-side gates contribution (precomputed each P_B; h_0 = 0 -> zero)
  i32x4 ahp[4];
#pragma unroll
  for (int i = 0; i < 4; ++i) ahp[i] = (i32x4){0, 0, 0, 0};
  __syncthreads();

  // ---- per-wave preloads (post-barrier: LDS constants now valid) ----
  float seM[4], ebM[4];
#pragma unroll
  for (int q = 0; q < 4; ++q) {
    seM[q] = s_se[q * 128 + phig];
    ebM[q] = s_encb[q * 128 + phig];
  }
  f32x4 webq = {0.f, 0.f, 0.f, 0.f};
  if (w < 4) webq = *(const f32x4*)&s_web[(w << 4) + ((lane >> 4) << 2)];

  // ====================== encoder ======================
  for (int t = 0; t < T_; ++t) {
    // ---- P_A: attention (w0-3, prio) | proj_{t-1} (w4-7) ----
    // proj reads s_Ahc = [h;c]_{t-1}, stable until P_GE(t) after B1.
    float x0, x1;
    if (w < 4) {
      __builtin_amdgcn_s_setprio(1);
      x0 = xf0; x1 = xf1;                 // prefetched one step ago
      // node eval: lane = (ni = lane>>3, kc = lane&7); 8 k-terms each
      const int kc = lane & 7;
      float p = 0.f;
      const float4* wvp = (const float4*)&s_wv[kc * 8];
      const float4* bp  = (const float4*)&s_base[w][kc * 8];
      float4 bA = bp[0], bB = bp[1];
#pragma unroll
      for (int q = 0; q < 4; ++q) {
        float4 wv = wvp[q];                       // (w_k, ve_k, w_{k+1}, ve_{k+1})
        float bb0 = (q < 2) ? ((q & 1) ? bA.z : bA.x) : ((q & 1) ? bB.z : bB.x);
        float bb1 = (q < 2) ? ((q & 1) ? bA.w : bA.y) : ((q & 1) ? bB.w : bB.y);
        p += wv.y * tanh_acc(fmaf(xi, wv.x, bb0));
        p += wv.w * tanh_acc(fmaf(xi, wv.z, bb1));
      }
      p = gsum8(p);                               // sum over kc within node grp
      // group-uniform after gsum8 -> readlane (VALU, no DS pipe)
      float f0 = rdlane(p,  0), f1 = rdlane(p,  8);
      float f2 = rdlane(p, 16), f3 = rdlane(p, 24);
      float f4 = rdlane(p, 32), f5 = rdlane(p, 40);
      float f6 = rdlane(p, 48), f7 = rdlane(p, 56);
      // Lagrange FIRST form at u = clamp(x, +-6): rcp-free.
      float e0, e1;
      {
        const float xb[8] = { 5.884711682f, 4.988817674f, 3.333421398f, 1.170541932f,
                             -1.170541932f, -3.333421398f, -4.988817674f, -5.884711682f};
        const float wbar[8] = { 0.1950903220f, -0.5555702330f, 0.8314696123f, -0.9807852804f,
                                0.9807852804f, -0.8314696123f, 0.5555702330f, -0.1950903220f};
        float fw[8] = {f0 * wbar[0], f1 * wbar[1], f2 * wbar[2], f3 * wbar[3],
                       f4 * wbar[4], f5 * wbar[5], f6 * wbar[6], f7 * wbar[7]};
        float u0 = fminf(fmaxf(x0, -6.f), 6.f), u1 = fminf(fmaxf(x1, -6.f), 6.f);
        float d0[8], d1[8], P0[8], P1[8];
        float pre0 = 1.f, pre1 = 1.f;
#pragma unroll
        for (int i = 0; i < 8; ++i) {
          d0[i] = u0 - xb[i]; d1[i] = u1 - xb[i];
          P0[i] = pre0;       P1[i] = pre1;
          pre0 *= d0[i];      pre1 *= d1[i];
        }
        float suf0 = 1.f, suf1 = 1.f, acc0 = 0.f, acc1 = 0.f;
#pragma unroll
        for (int i = 7; i >= 0; --i) {
          acc0 = fmaf(fw[i] * P0[i], suf0, acc0);
          acc1 = fmaf(fw[i] * P1[i], suf1, acc1);
          suf0 *= d0[i];
          suf1 *= d1[i];
        }
        e0 = fexp2(acc0 * KLAG);                  // exp(sc), sc=acc/17496
        e1 = fexp2(acc1 * KLAG);
      }
      float sum = wsum64(e0 + e1);
      float mx  = wmax64(fmaxf(e0 * fabsf(x0), e1 * fabsf(x1)));
      float inv = mx > 0.f ? 127.f * frcp(mx) : 0.f;
      s_A8[w][lane]      = (char)(int)rintf(x0 * e0 * inv);
      s_A8[w][64 + lane] = (char)(int)rintf(x1 * e1 * inv);
      if (lane == 0) s_xr[w] = mx * frcp(127.f * sum);
      __builtin_amdgcn_s_setprio(0);
    } else if (t > 0) {
      f32x4 acc = {0.f, 0.f, 0.f, 0.f};
#pragma unroll
      for (int kt = 0; kt < 4; ++kt) {
        bf16x8 a = *(const bf16x8*)&s_Ahc[lane & 15][kt * 32 + ((lane >> 4) << 3)];
        acc = MFMA16(a, wp[kt], acc);    // original orientation (strided store)
      }
      if (lane < 16) {
        int katt = (w - 4) * 16 + lane;
#pragma unroll
        for (int r = 0; r < 4; ++r) s_projT[r][katt][t - 1] = f2b(acc[r]);
      }
    }
    __syncthreads();                                            // B1
    // ---- P_GE: gates i8 GEMM (C^T) + IN-WAVE transpose + fused epilogue ----
    {
      i32x4 a0 = *(const i32x4*)&s_A8[lane & 15][  0 + ((lane >> 4) << 4)];
      i32x4 a1 = *(const i32x4*)&s_A8[lane & 15][ 64 + ((lane >> 4) << 4)];
      i32x4 ax[4];
#pragma unroll
      for (int i = 0; i < 4; ++i) {
        i32x4 z = {0, 0, 0, 0};
        ax[i] = MFMAI8(wg[1][i], a1, MFMAI8(wg[0][i], a0, z));
      }
      float* scr = ((float*)s_gates) + w * 264;   // per-wave 256 f32 scratch
      float sx = s_xr[lane & 3];
      if ((lane & 15) < 4) {
        int off = ((lane & 15) << 4) + ((lane >> 4) << 2);  // brow*16 + col
#pragma unroll
        for (int i = 0; i < 4; ++i) {
          f32x4 v;
#pragma unroll
          for (int r = 0; r < 4; ++r)
            v[r] = fmaf(sx, (float)ax[i][r], C127 * (float)ahp[i][r]);
          *(f32x4*)&scr[i * 64 + off] = v;
        }
      }
      asm volatile("" ::: "memory");  // keep write->read program order
      // read back transposed: gate q of cell (bM, phil) at [q*64 + bM*16 + phil]
      int ra = (bM << 4) + phil;
      float g_i = fmaf(scr[      ra], seM[0], ebM[0]);
      float g_f = fmaf(scr[ 64 + ra], seM[1], ebM[1]);
      float g_g = fmaf(scr[128 + ra], seM[2], ebM[2]);
      float g_o = fmaf(scr[192 + ra], seM[3], ebM[3]);
      cM = sigm(g_f) * cM + sigm(g_i) * tanh_acc(g_g);
      float h = sigm(g_o) * tanh_acc(cM);
      s_Ahc[bM][phig]       = f2b(h);
      s_Ahc[bM][128 + phig] = f2b(cM);
      s_A8[bM][128 + phig]  = (char)(int)rintf(h * 127.f);
      s_encht[bM][phig][t]  = f2b(h);
    }
    __syncthreads();                                            // B2
    // ---- P_B: base_{t+1} (w0-3, transposed) ; ah-precompute (all waves) ----
    {
      i32x4 pa2 = *(const i32x4*)&s_A8[lane & 15][128 + ((lane >> 4) << 4)];
      i32x4 pa3 = *(const i32x4*)&s_A8[lane & 15][192 + ((lane >> 4) << 4)];
#pragma unroll
      for (int i = 0; i < 4; ++i) {
        i32x4 z = {0, 0, 0, 0};
        ahp[i] = MFMAI8(wg[3][i], pa3, MFMAI8(wg[2][i], pa2, z));
      }
    }
    if (w < 4) {
      if (t < T_ - 1) {                   // X prefetch: one full step early
        xf0 = Xr[(t + 1) * D_ + lane];
        xf1 = Xr[(t + 1) * D_ + 64 + lane];
      }
      f32x4 acc = {0.f, 0.f, 0.f, 0.f}, acc2 = {0.f, 0.f, 0.f, 0.f};
#pragma unroll
      for (int kt = 0; kt < 4; ++kt) {
        bf16x8 a = *(const bf16x8*)&s_Ahc[lane & 15][kt * 32 + ((lane >> 4) << 3)];
        acc = MFMA16(wb[kt], a, acc);
      }
#pragma unroll
      for (int kt = 4; kt < 8; ++kt) {
        bf16x8 a = *(const bf16x8*)&s_Ahc[lane & 15][kt * 32 + ((lane >> 4) << 3)];
        acc2 = MFMA16(wb[kt], a, acc2);
      }
      if ((lane & 15) < 4) {
        f32x4 v = acc + acc2 + webq;
        *(f32x4*)&s_base[lane & 15][(w << 4) + ((lane >> 4) << 2)] = v;
      }
    }
    __syncthreads();                                            // B3
  }
  // ---- final proj(T-1) (w4-7; s_Ahc still holds [h;c]_{T-1}) ----
  if (w >= 4) {
    f32x4 acc = {0.f, 0.f, 0.f, 0.f};
#pragma unroll
    for (int kt = 0; kt < 4; ++kt) {
      bf16x8 a = *(const bf16x8*)&s_Ahc[lane & 15][kt * 32 + ((lane >> 4) << 3)];
      acc = MFMA16(a, wp[kt], acc);
    }
    if (lane < 16) {
      int katt = (w - 4) * 16 + lane;
#pragma unroll
      for (int r = 0; r < 4; ++r) s_projT[r][katt][T_ - 1] = f2b(acc[r]);
    }
  }
  __syncthreads();

  // ====================== decoder ======================
  {
    int r = tid >> 7, j = tid & 127;
    s_Ahc[r][j] = 0; s_Ahc[r][128 + j] = 0; s_A8[r][j] = 0;
  }
  i32x4 wdg[2][8];                      // dec gates i8 (waves 4-7), nt=(w-4)*8+i
  bf16x8 wdc[8];                        // dc bf16 (waves 0-3)
  float yp = 0.f, yhd = 0.f;
  float sdC_p[8], db_p[8], dw_p[8];
  f32x4 wdbq = {0.f, 0.f, 0.f, 0.f};
  if (w >= 4) {
#pragma unroll
    for (int kt = 0; kt < 2; ++kt)
#pragma unroll
      for (int i = 0; i < 8; ++i)
        wdg[kt][i] = dec8[(kt * 32 + ((w - 4) * 8 + i)) * 64 + lane];
  } else {
#pragma unroll
    for (int kt = 0; kt < 8; ++kt)
      wdc[kt] = *(const bf16x8*)(f16 + WDDC_E + ((kt * 4 + w) * 64 + lane) * 8);
#pragma unroll
    for (int j = 0; j < 8; ++j) {
      sdC_p[j] = s_sd[lane + 64 * j] * C127;
      db_p[j]  = s_decb[lane + 64 * j];
      dw_p[j]  = s_dwih[lane + 64 * j];
    }
    wdbq = *(const f32x4*)&s_wdb[(w << 4) + ((lane >> 4) << 2)];
    yp = y_hist[(b0 + w) * T_ + (T_ - 1)];
    float pp = s_fcw[256 + lane] * y_hist[(b0 + w) * T_ + lane];
    yhd = wsum64(pp) + fc_b[0];
  }
  float dd0 = 0.f, dc0 = 0.f, dd1 = 0.f, dc1 = 0.f;   // d, cc (2 feats/lane)
  __syncthreads();

  for (int hs = 0; hs < HOR_; ++hs) {
    // ---- Phase A: w0-3 {context+fc+out(hs-1), dc GEMM} | w4-7 {gates GEMM}
    if (w >= 4) {
      i32x4 a0 = *(const i32x4*)&s_A8[lane & 15][ 0 + ((lane >> 4) << 4)];
      i32x4 a1 = *(const i32x4*)&s_A8[lane & 15][64 + ((lane >> 4) << 4)];
#pragma unroll
      for (int i = 0; i < 8; ++i) {
        i32x4 z = {0, 0, 0, 0};
        i32x4 ac = MFMAI8(wdg[1][i], a1, MFMAI8(wdg[0][i], a0, z));
        if ((lane & 15) < 4) {
          f32x4 v = {(float)ac[0], (float)ac[1], (float)ac[2], (float)ac[3]};
          *(f32x4*)&s_gates[lane & 15][(((w - 4) * 8 + i) << 4) + ((lane >> 4) << 2)] = v;
        }
      }
    } else {
      if (hs > 0) {
        // context for step hs-1 (beta from last Phase B) + fc + out
        float cx0a = 0.f, cx0b = 0.f, cx1a = 0.f, cx1b = 0.f;
        const short* e0p = &s_encht[w][lane][0];
        const short* e1p = &s_encht[w][lane + 64][0];
#pragma unroll 8
        for (int tp = 0; tp < 32; ++tp) {
          float2 bta = *(const float2*)&s_beta[w][2 * tp];
          short2 h0v = *(const short2*)&e0p[2 * tp];
          short2 h1v = *(const short2*)&e1p[2 * tp];
          cx0a = fmaf(bta.x, b2f(h0v.x), cx0a); cx0b = fmaf(bta.y, b2f(h0v.y), cx0b);
          cx1a = fmaf(bta.x, b2f(h1v.x), cx1a); cx1b = fmaf(bta.y, b2f(h1v.y), cx1b);
        }
        float cx0 = cx0a + cx0b, cx1 = cx1a + cx1b;
        float pf = s_fcw[lane] * dd0 + s_fcw[64 + lane] * dd1
                 + s_fcw[128 + lane] * cx0 + s_fcw[192 + lane] * cx1;
        pf = wsum64(pf);
        float o = pf + yhd;
        if (lane == 0) out[(b0 + w) * HOR_ + (hs - 1)] = o;
        yp = o;
      }
      // dc GEMM (reads s_Ahc = d_hs written last Phase B)
      f32x4 acc = {0.f, 0.f, 0.f, 0.f}, acc2 = {0.f, 0.f, 0.f, 0.f};
#pragma unroll
      for (int kt = 0; kt < 4; ++kt) {
        bf16x8 a = *(const bf16x8*)&s_Ahc[lane & 15][kt * 32 + ((lane >> 4) << 3)];
        acc = MFMA16(wdc[kt], a, acc);
      }
#pragma unroll
      for (int kt = 4; kt < 8; ++kt) {
        bf16x8 a = *(const bf16x8*)&s_Ahc[lane & 15][kt * 32 + ((lane >> 4) << 3)];
        acc2 = MFMA16(wdc[kt], a, acc2);
      }
      if ((lane & 15) < 4) {
        f32x4 v = acc + acc2 + wdbq;
        *(f32x4*)&s_base[lane & 15][(w << 4) + ((lane >> 4) << 2)] = v;
      }
    }
    __syncthreads();                                            // B1
    // ---- Phase B: w0-3 {LSTM epilogue} | w4-7 {scores+softmax, prio} ----
    if (w < 4) {
      float gi0 = s_gates[w][lane]       * sdC_p[0] + db_p[0] + yp * dw_p[0];
      float gi1 = s_gates[w][lane + 64]  * sdC_p[1] + db_p[1] + yp * dw_p[1];
      float gf0 = s_gates[w][lane + 128] * sdC_p[2] + db_p[2] + yp * dw_p[2];
      float gf1 = s_gates[w][lane + 192] * sdC_p[3] + db_p[3] + yp * dw_p[3];
      float gg0 = s_gates[w][lane + 256] * sdC_p[4] + db_p[4] + yp * dw_p[4];
      float gg1 = s_gates[w][lane + 320] * sdC_p[5] + db_p[5] + yp * dw_p[5];
      float go0 = s_gates[w][lane + 384] * sdC_p[6] + db_p[6] + yp * dw_p[6];
      float go1 = s_gates[w][lane + 448] * sdC_p[7] + db_p[7] + yp * dw_p[7];
      dc0 = sigm(gf0) * dc0 + sigm(gi0) * tanh_acc(gg0);
      dd0 = sigm(go0) * tanh_acc(dc0);
      dc1 = sigm(gf1) * dc1 + sigm(gi1) * tanh_acc(gg1);
      dd1 = sigm(go1) * tanh_acc(dc1);
      // state for next Phase A GEMMs
      s_Ahc[w][lane]       = f2b(dd0);
      s_Ahc[w][lane + 64]  = f2b(dd1);
      s_Ahc[w][lane + 128] = f2b(dc0);
      s_Ahc[w][lane + 192] = f2b(dc1);
      s_A8[w][lane]      = (char)(int)rintf(dd0 * 127.f);
      s_A8[w][lane + 64] = (char)(int)rintf(dd1 * 127.f);
    } else {
      __builtin_amdgcn_s_setprio(1);
      const int r = w - 4;
      float sA = 0.f, sB = 0.f, sC = 0.f, sD = 0.f;
#pragma unroll 4
      for (int k = 0; k < 64; k += 4) {
        sA += s_vd[k]     * tanh_acc(b2f(s_projT[r][k][lane])     + s_base[r][k]);
        sB += s_vd[k + 1] * tanh_acc(b2f(s_projT[r][k + 1][lane]) + s_base[r][k + 1]);
        sC += s_vd[k + 2] * tanh_acc(b2f(s_projT[r][k + 2][lane]) + s_base[r][k + 2]);
        sD += s_vd[k + 3] * tanh_acc(b2f(s_projT[r][k + 3][lane]) + s_base[r][k + 3]);
      }
      float s = (sA + sB) + (sC + sD);
      float e = fexp2(s * LOG2E);
      float ssum = wsum64(e);
      s_beta[r][lane] = e * frcp(ssum);
      __builtin_amdgcn_s_setprio(0);
    }
    __syncthreads();                                            // B2
  }
  // ---- tail: final context+fc+out for hs = HOR_-1 (w0-3) ----
  if (w < 4) {
    float cx0a = 0.f, cx0b = 0.f, cx1a = 0.f, cx1b = 0.f;
    const short* e0p = &s_encht[w][lane][0];
    const short* e1p = &s_encht[w][lane + 64][0];
#pragma unroll 8
    for (int tp = 0; tp < 32; ++tp) {
      float2 bta = *(const float2*)&s_beta[w][2 * tp];
      short2 h0v = *(const short2*)&e0p[2 * tp];
      short2 h1v = *(const short2*)&e1p[2 * tp];
      cx0a = fmaf(bta.x, b2f(h0v.x), cx0a); cx0b = fmaf(bta.y, b2f(h0v.y), cx0b);
      cx1a = fmaf(bta.x, b2f(h1v.x), cx1a); cx1b = fmaf(bta.y, b2f(h1v.y), cx1b);
    }
    float cx0 = cx0a + cx0b, cx1 = cx1a + cx1b;
    float pf = s_fcw[lane] * dd0 + s_fcw[64 + lane] * dd1
             + s_fcw[128 + lane] * cx0 + s_fcw[192 + lane] * cx1;
    pf = wsum64(pf);
    float o = pf + yhd;
    if (lane == 0) out[(b0 + w) * HOR_ + (HOR_ - 1)] = o;
  }
}

extern "C" void kernel_launch(void* const* d_in, const int* in_sizes, int n_in,
                              void* d_out, int out_size, void* d_ws, size_t ws_size,
                              hipStream_t stream) {
  (void)in_sizes; (void)n_in; (void)out_size; (void)ws_size;
  const float* X       = (const float*)d_in[0];
  const float* y_hist  = (const float*)d_in[1];
  const float* We_w    = (const float*)d_in[2];
  const float* We_b    = (const float*)d_in[3];
  const float* ve_w    = (const float*)d_in[4];
  // d_in[5] = ve_b : softmax-invariant, unused
  const float* enc_Wih = (const float*)d_in[6];
  const float* enc_Whh = (const float*)d_in[7];
  const float* enc_bih = (const float*)d_in[8];
  const float* enc_bhh = (const float*)d_in[9];
  const float* dec_Wih = (const float*)d_in[10];
  const float* dec_Whh = (const float*)d_in[11];
  const float* dec_bih = (const float*)d_in[12];
  const float* dec_bhh = (const float*)d_in[13];
  const float* Wd_w    = (const float*)d_in[14];
  const float* Wd_b    = (const float*)d_in[15];
  const float* vd_w    = (const float*)d_in[16];
  // d_in[17] = vd_b : softmax-invariant, unused
  const float* fc_w    = (const float*)d_in[18];
  const float* fc_b    = (const float*)d_in[19];

  char* ws8  = (char*)d_ws;
  float* out = (float*)d_out;

  prep_bf<<<160, 256, 0, stream>>>(We_w, Wd_w, ws8);
  prep_q <<<256, 256, 0, stream>>>(enc_Wih, enc_Whh, dec_Whh, ws8);
  da_rnn <<<B_ / BB, 512, 0, stream>>>(X, y_hist, We_w, We_b, ve_w,
                                       enc_bih, enc_bhh, dec_Wih, dec_bih, dec_bhh,
                                       Wd_b, vd_w, fc_w, fc_b, ws8, out);
}

// Round 13
// 289.825 us; speedup vs baseline: 1.0237x; 1.0054x over previous
//
#include <hip/hip_runtime.h>
#include <hip/hip_bf16.h>

// DA-RNN persistent kernel, round 19: decoder Phase-A pole split.
// R18 confirmed (203us). Remaining imbalance: dec Phase A w0-3 carry
// context(96 LDS reads + ~400 VALU) + fc + dc GEMM (~1000cy) vs w4-7 gates
// GEMM (~400cy). R19 splits context by feature halves: wave r keeps j<64
// (cx0 + dd-terms of fc), wave r+4 computes j>=64 (cx1) after its gates
// GEMM; partial fc sums land in s_pf[4][2]; combine+out+yp moves to top of
// Phase B (w0-3) where the LDS read overlaps the s_gates chain head.
// Phase B pole (w4-7 scores) unchanged. Hazards: s_beta[r] same-wave for
// r+4 / crosses B2 for r; s_pf crosses B1 (w->r) and B2 (r->w); yp guarded
// at hs=0; tail unchanged. fc reduction splits into two wsum64 partials
// (+-1ulp). Everything else = R18 verbatim.
// BB=4, 256 blocks, __launch_bounds__(512,2): proven no-spill regime.

#define B_    1024
#define T_    64
#define D_    128
#define H_    128
#define HOR_  24
#define ATT_  64
#define BB    4
#define LOG2E 1.4426950408889634f
#define C127  (1.f/127.f)
// LOG2E / 17496 (Lagrange first-form normalization folded into exp2 arg)
#define KLAG  8.245856315e-05f

typedef float f32x4  __attribute__((ext_vector_type(4)));
typedef short bf16x8 __attribute__((ext_vector_type(8)));
typedef int   i32x4  __attribute__((ext_vector_type(4)));

#define MFMA16(a,b,c) __builtin_amdgcn_mfma_f32_16x16x32_bf16((a),(b),(c),0,0,0)
#define MFMAI8(a,b,c) __builtin_amdgcn_mfma_i32_16x16x64_i8((a),(b),(c),0,0,0)

// ---- workspace layout (same packing as R5..R18) ----
#define WHS_E    0        // base GEMM  B bf16: kt0..7, nt0..3  (16384 el)
#define WDDC_E   16384    // dc GEMM    B bf16: kt0..7, nt0..3  (16384 el)
#define WDENC_E  32768    // proj GEMM  B bf16: kt0..3, nt0..3  ( 8192 el)
#define WENC8_B  81920    // i8 enc gates B: [kt4][nt32][lane64][16] (131072 B)
#define WDEC8_B  212992   // i8 dec gates B: [kt2][nt32][lane64][16] ( 65536 B)
#define SENC_B   278528   // 512 f32 per-col scales (enc)
#define SDEC_B   280576   // 512 f32 per-col scales (dec)

__device__ __forceinline__ short f2b(float f) {        // fp32 -> bf16 RNE
  union { float f; unsigned u; } c; c.f = f;
  unsigned r = c.u + 0x7fffu + ((c.u >> 16) & 1u);
  return (short)(r >> 16);
}
__device__ __forceinline__ float b2f(short s) {
  union { unsigned u; float f; } c; c.u = ((unsigned)(unsigned short)s) << 16;
  return c.f;
}
__device__ __forceinline__ float fexp2(float x) { return __builtin_amdgcn_exp2f(x); }
__device__ __forceinline__ float frcp (float x) { return __builtin_amdgcn_rcpf(x); }
__device__ __forceinline__ float tanh_acc(float x) {   // 1 - 2/(1+e^{2x})
  float e = fexp2(x * 2.885390081777927f);
  return 1.f - 2.f * frcp(1.f + e);
}
__device__ __forceinline__ float sigm(float x) {
  return frcp(1.f + fexp2(-LOG2E * x));
}

// ---- fast cross-lane: DPP xor1/2/4/8, ds_swizzle xor16, shfl xor32 ----
template<int CTRL>
__device__ __forceinline__ float dppmov(float v) {
  return __builtin_bit_cast(float,
      __builtin_amdgcn_mov_dpp(__builtin_bit_cast(int, v), CTRL, 0xF, 0xF, true));
}
__device__ __forceinline__ float swz16(float v) {      // lane ^= 16
  return __builtin_bit_cast(float,
      __builtin_amdgcn_ds_swizzle(__builtin_bit_cast(int, v), 0x401F));
}
__device__ __forceinline__ float rdlane(float v, int l) {  // wave-uniform read
  return __builtin_bit_cast(float,
      __builtin_amdgcn_readlane(__builtin_bit_cast(int, v), l));
}
__device__ __forceinline__ float wsum64(float v) {
  v += dppmov<0xB1>(v);        // xor1  (quad_perm 1,0,3,2)
  v += dppmov<0x4E>(v);        // xor2  (quad_perm 2,3,0,1)
  v += dppmov<0x141>(v);       // xor4  (row_half_mirror)
  v += dppmov<0x140>(v);       // xor8  (row_mirror)
  v += swz16(v);               // xor16
  v += __shfl_xor(v, 32, 64);  // xor32 (permlane32_swap UNSAFE when aliased - R12)
  return v;
}
__device__ __forceinline__ float wmax64(float v) {
  v = fmaxf(v, dppmov<0xB1>(v));
  v = fmaxf(v, dppmov<0x4E>(v));
  v = fmaxf(v, dppmov<0x141>(v));
  v = fmaxf(v, dppmov<0x140>(v));
  v = fmaxf(v, swz16(v));
  v = fmaxf(v, __shfl_xor(v, 32, 64));
  return v;
}
__device__ __forceinline__ float gsum8(float v) {      // sum within group of 8
  v += dppmov<0xB1>(v);
  v += dppmov<0x4E>(v);
  v += dppmov<0x141>(v);
  return v;
}

// ---- prep1: bf16 B-frags (base / dc / proj), one element per thread ----
__global__ void prep_bf(const float* __restrict__ We_w,
                        const float* __restrict__ Wd_w,
                        char* __restrict__ ws8) {
  int e = blockIdx.x * 256 + threadIdx.x;
  if (e >= 40960) return;
  short* f16 = (short*)ws8;
  int region = e >> 14;                  // 0=WHS 1=WDDC 2=WDENC
  int er = e & 16383;
  int fi = er >> 9, li = (er >> 3) & 63, jq = er & 7;
  int kt = fi >> 2, nt = fi & 3;
  int k = kt * 32 + ((li >> 4) << 3) + jq, n = nt * 16 + (li & 15);
  float v;
  if (region == 0)      v = We_w[n * 257 + k];
  else if (region == 1) v = (k < 128) ? Wd_w[n * 384 + 128 + k]
                                      : Wd_w[n * 384 + 256 + (k - 128)];
  else                  v = Wd_w[n * 384 + k];
  f16[e] = f2b(v);
}

// ---- prep2: i8 quantized gates weights, one wave per column ----
__global__ void prep_q(const float* __restrict__ enc_Wih,
                       const float* __restrict__ enc_Whh,
                       const float* __restrict__ dec_Whh,
                       char* __restrict__ ws8) {
  int gw = (blockIdx.x * 256 + threadIdx.x) >> 6;
  int lane = threadIdx.x & 63;
  if (gw < 512) {                        // encoder col, K=256
    int n = gw;
    float v[4]; float m = 0.f;
#pragma unroll
    for (int q = 0; q < 4; ++q) {
      int k = lane * 4 + q;
      v[q] = (k < 128) ? enc_Wih[n * 128 + k] : enc_Whh[n * 128 + (k - 128)];
      m = fmaxf(m, fabsf(v[q]));
    }
    m = wmax64(m);
    if (lane == 0) ((float*)(ws8 + SENC_B))[n] = m * C127;
    float inv = m > 0.f ? 127.f / m : 0.f;
    char* dst = ws8 + WENC8_B;
#pragma unroll
    for (int q = 0; q < 4; ++q) {
      int k = lane * 4 + q;
      int kt = k >> 6, grp = (k >> 4) & 3, b = k & 15, l16 = (n & 15) | (grp << 4);
      dst[((kt * 32 + (n >> 4)) * 64 + l16) * 16 + b] = (char)(int)rintf(v[q] * inv);
    }
  } else if (gw < 1024) {                // decoder col, K=128
    int n = gw - 512;
    float v[2]; float m = 0.f;
#pragma unroll
    for (int q = 0; q < 2; ++q) {
      int k = lane * 2 + q;
      v[q] = dec_Whh[n * 128 + k];
      m = fmaxf(m, fabsf(v[q]));
    }
    m = wmax64(m);
    if (lane == 0) ((float*)(ws8 + SDEC_B))[n] = m * C127;
    float inv = m > 0.f ? 127.f / m : 0.f;
    char* dst = ws8 + WDEC8_B;
#pragma unroll
    for (int q = 0; q < 2; ++q) {
      int k = lane * 2 + q;
      int kt = k >> 6, grp = (k >> 4) & 3, b = k & 15, l16 = (n & 15) | (grp << 4);
      dst[((kt * 32 + (n >> 4)) * 64 + l16) * 16 + b] = (char)(int)rintf(v[q] * inv);
    }
  }
}

__global__ __launch_bounds__(512, 2)
void da_rnn(const float* __restrict__ X, const float* __restrict__ y_hist,
            const float* __restrict__ We_w, const float* __restrict__ We_b,
            const float* __restrict__ ve_w,
            const float* __restrict__ enc_bih, const float* __restrict__ enc_bhh,
            const float* __restrict__ dec_Wih,
            const float* __restrict__ dec_bih, const float* __restrict__ dec_bhh,
            const float* __restrict__ Wd_b, const float* __restrict__ vd_w,
            const float* __restrict__ fc_w, const float* __restrict__ fc_b,
            const char* __restrict__ ws8, float* __restrict__ out) {
  const short* f16  = (const short*)ws8;
  const i32x4* enc8 = (const i32x4*)(ws8 + WENC8_B);
  const i32x4* dec8 = (const i32x4*)(ws8 + WDEC8_B);
  const float* senc = (const float*)(ws8 + SENC_B);
  const float* sdec = (const float*)(ws8 + SDEC_B);

  // strides mod 32 words: s_A8 68=4, s_Ahc 132=4, s_gates 528=16, s_base 72=8
  __shared__ __align__(16) char  s_A8[16][272];   // gates A i8
  __shared__ __align__(16) short s_Ahc[16][264];  // base/dc/proj A bf16 [h;c]
  __shared__ short s_projT[4][64][65];            // enc_proj^T
  __shared__ short s_encht[4][128][66];           // enc_hiddens [r][j][t] bf16
  __shared__ __align__(16) float s_gates[4][528]; // dec gates / enc per-wave scratch
  __shared__ __align__(16) float s_base[4][72];   // enc: base ; dec: dc
  __shared__ float s_beta[4][64];
  __shared__ float s_pf[4][2];                    // dec fc partials (j<64, j>=64)
  __shared__ float s_xr[4];
  __shared__ float2 s_wv[64];                     // (w_feat[k], ve_w[k])
  __shared__ __align__(16) float s_web[64];
  __shared__ float s_vd[64];
  __shared__ __align__(16) float s_wdb[64];
  __shared__ float s_se[512], s_sd[512];
  __shared__ float s_encb[512], s_decb[512], s_dwih[512];
  __shared__ float s_fcw[320];

  const int tid  = threadIdx.x;
  const int lane = tid & 63;
  const int w    = tid >> 6;        // wave 0..7 ; waves 0-3 own row w
  const int b0   = blockIdx.x * BB;

  // ---- init ----
  if (tid < 64) {
    s_wv[tid]  = make_float2(We_w[tid * 257 + 256], ve_w[tid]);
    s_web[tid] = We_b[tid];
    s_vd[tid]  = vd_w[tid];
    s_wdb[tid] = Wd_b[tid];
  }
  if (tid < 320) s_fcw[tid] = fc_w[tid];
  s_se[tid]   = senc[tid];
  s_sd[tid]   = sdec[tid];
  s_encb[tid] = enc_bih[tid] + enc_bhh[tid];
  s_decb[tid] = dec_bih[tid] + dec_bhh[tid];
  s_dwih[tid] = dec_Wih[tid];
  for (int i = tid; i < (16 * 272) / 4; i += 512) ((int*)s_A8)[i] = 0;
  for (int i = tid; i < (16 * 264) / 2; i += 512) ((int*)s_Ahc)[i] = 0;
  if (tid < 256) s_base[tid >> 6][tid & 63] = We_b[tid & 63];  // base_0

  // ---- register-resident weights (loaded once, L2) ----
  i32x4 wg[4][4];                       // enc gates i8, nt = w + 8i
#pragma unroll
  for (int kt = 0; kt < 4; ++kt)
#pragma unroll
    for (int i = 0; i < 4; ++i)
      wg[kt][i] = enc8[(kt * 32 + (w + 8 * i)) * 64 + lane];
  bf16x8 wb[8], wp[4];
  if (w < 4) {
#pragma unroll
    for (int kt = 0; kt < 8; ++kt)
      wb[kt] = *(const bf16x8*)(f16 + WHS_E + ((kt * 4 + w) * 64 + lane) * 8);
  } else {
#pragma unroll
    for (int kt = 0; kt < 4; ++kt)
      wp[kt] = *(const bf16x8*)(f16 + WDENC_E + ((kt * 4 + (w - 4)) * 64 + lane) * 8);
  }

  // per-row attention state (waves 0-3): features j0=lane, j1=lane+64
  float xf0 = 0.f, xf1 = 0.f, xi = 0.f;
  const float* Xr = X + (size_t)(b0 + (w & 3)) * T_ * D_;
  if (w < 4) {
    xf0 = Xr[lane]; xf1 = Xr[64 + lane];    // x(t=0), consumed top of P_A(0)
    xi = 6.f * cosf((2 * (lane >> 3) + 1) * 0.19634954084936207f);  // node
  }
  // merged-epilogue cell: wave w owns features 16w..16w+15 x rows 0..3
  //   cell = (row bM = lane>>4, feature phig = 16w + (lane&15))
  float cM = 0.f;
  const int bM   = lane >> 4;
  const int phil = lane & 15;
  const int phig = (w << 4) + phil;
  // h-side gates contribution (precomputed each P_B; h_0 = 0 -> zero)
  i32x4 ahp[4];
#pragma unroll
  for (int i = 0; i < 4; ++i) ahp[i] = (i32x4){0, 0, 0, 0};
  __syncthreads();

  // ---- per-wave preloads (post-barrier: LDS constants now valid) ----
  float seM[4], ebM[4];
#pragma unroll
  for (int q = 0; q < 4; ++q) {
    seM[q] = s_se[q * 128 + phig];
    ebM[q] = s_encb[q * 128 + phig];
  }
  f32x4 webq = {0.f, 0.f, 0.f, 0.f};
  if (w < 4) webq = *(const f32x4*)&s_web[(w << 4) + ((lane >> 4) << 2)];

  // ====================== encoder ======================
  for (int t = 0; t < T_; ++t) {
    // ---- P_A: attention (w0-3, prio) | proj_{t-1} (w4-7) ----
    // proj reads s_Ahc = [h;c]_{t-1}, stable until P_GE(t) after B1.
    float x0, x1;
    if (w < 4) {
      __builtin_amdgcn_s_setprio(1);
      x0 = xf0; x1 = xf1;                 // prefetched one step ago
      // node eval: lane = (ni = lane>>3, kc = lane&7); 8 k-terms each
      const int kc = lane & 7;
      float p = 0.f;
      const float4* wvp = (const float4*)&s_wv[kc * 8];
      const float4* bp  = (const float4*)&s_base[w][kc * 8];
      float4 bA = bp[0], bB = bp[1];
#pragma unroll
      for (int q = 0; q < 4; ++q) {
        float4 wv = wvp[q];                       // (w_k, ve_k, w_{k+1}, ve_{k+1})
        float bb0 = (q < 2) ? ((q & 1) ? bA.z : bA.x) : ((q & 1) ? bB.z : bB.x);
        float bb1 = (q < 2) ? ((q & 1) ? bA.w : bA.y) : ((q & 1) ? bB.w : bB.y);
        p += wv.y * tanh_acc(fmaf(xi, wv.x, bb0));
        p += wv.w * tanh_acc(fmaf(xi, wv.z, bb1));
      }
      p = gsum8(p);                               // sum over kc within node grp
      // group-uniform after gsum8 -> readlane (VALU, no DS pipe)
      float f0 = rdlane(p,  0), f1 = rdlane(p,  8);
      float f2 = rdlane(p, 16), f3 = rdlane(p, 24);
      float f4 = rdlane(p, 32), f5 = rdlane(p, 40);
      float f6 = rdlane(p, 48), f7 = rdlane(p, 56);
      // Lagrange FIRST form at u = clamp(x, +-6): rcp-free.
      float e0, e1;
      {
        const float xb[8] = { 5.884711682f, 4.988817674f, 3.333421398f, 1.170541932f,
                             -1.170541932f, -3.333421398f, -4.988817674f, -5.884711682f};
        const float wbar[8] = { 0.1950903220f, -0.5555702330f, 0.8314696123f, -0.9807852804f,
                                0.9807852804f, -0.8314696123f, 0.5555702330f, -0.1950903220f};
        float fw[8] = {f0 * wbar[0], f1 * wbar[1], f2 * wbar[2], f3 * wbar[3],
                       f4 * wbar[4], f5 * wbar[5], f6 * wbar[6], f7 * wbar[7]};
        float u0 = fminf(fmaxf(x0, -6.f), 6.f), u1 = fminf(fmaxf(x1, -6.f), 6.f);
        float d0[8], d1[8], P0[8], P1[8];
        float pre0 = 1.f, pre1 = 1.f;
#pragma unroll
        for (int i = 0; i < 8; ++i) {
          d0[i] = u0 - xb[i]; d1[i] = u1 - xb[i];
          P0[i] = pre0;       P1[i] = pre1;
          pre0 *= d0[i];      pre1 *= d1[i];
        }
        float suf0 = 1.f, suf1 = 1.f, acc0 = 0.f, acc1 = 0.f;
#pragma unroll
        for (int i = 7; i >= 0; --i) {
          acc0 = fmaf(fw[i] * P0[i], suf0, acc0);
          acc1 = fmaf(fw[i] * P1[i], suf1, acc1);
          suf0 *= d0[i];
          suf1 *= d1[i];
        }
        e0 = fexp2(acc0 * KLAG);                  // exp(sc), sc=acc/17496
        e1 = fexp2(acc1 * KLAG);
      }
      float sum = wsum64(e0 + e1);
      float mx  = wmax64(fmaxf(e0 * fabsf(x0), e1 * fabsf(x1)));
      float inv = mx > 0.f ? 127.f * frcp(mx) : 0.f;
      s_A8[w][lane]      = (char)(int)rintf(x0 * e0 * inv);
      s_A8[w][64 + lane] = (char)(int)rintf(x1 * e1 * inv);
      if (lane == 0) s_xr[w] = mx * frcp(127.f * sum);
      __builtin_amdgcn_s_setprio(0);
    } else if (t > 0) {
      f32x4 acc = {0.f, 0.f, 0.f, 0.f};
#pragma unroll
      for (int kt = 0; kt < 4; ++kt) {
        bf16x8 a = *(const bf16x8*)&s_Ahc[lane & 15][kt * 32 + ((lane >> 4) << 3)];
        acc = MFMA16(a, wp[kt], acc);    // original orientation (strided store)
      }
      if (lane < 16) {
        int katt = (w - 4) * 16 + lane;
#pragma unroll
        for (int r = 0; r < 4; ++r) s_projT[r][katt][t - 1] = f2b(acc[r]);
      }
    }
    __syncthreads();                                            // B1
    // ---- P_GE: gates i8 GEMM (C^T) + IN-WAVE transpose + fused epilogue ----
    {
      i32x4 a0 = *(const i32x4*)&s_A8[lane & 15][  0 + ((lane >> 4) << 4)];
      i32x4 a1 = *(const i32x4*)&s_A8[lane & 15][ 64 + ((lane >> 4) << 4)];
      i32x4 ax[4];
#pragma unroll
      for (int i = 0; i < 4; ++i) {
        i32x4 z = {0, 0, 0, 0};
        ax[i] = MFMAI8(wg[1][i], a1, MFMAI8(wg[0][i], a0, z));
      }
      float* scr = ((float*)s_gates) + w * 264;   // per-wave 256 f32 scratch
      float sx = s_xr[lane & 3];
      if ((lane & 15) < 4) {
        int off = ((lane & 15) << 4) + ((lane >> 4) << 2);  // brow*16 + col
#pragma unroll
        for (int i = 0; i < 4; ++i) {
          f32x4 v;
#pragma unroll
          for (int r = 0; r < 4; ++r)
            v[r] = fmaf(sx, (float)ax[i][r], C127 * (float)ahp[i][r]);
          *(f32x4*)&scr[i * 64 + off] = v;
        }
      }
      asm volatile("" ::: "memory");  // keep write->read program order
      // read back transposed: gate q of cell (bM, phil) at [q*64 + bM*16 + phil]
      int ra = (bM << 4) + phil;
      float g_i = fmaf(scr[      ra], seM[0], ebM[0]);
      float g_f = fmaf(scr[ 64 + ra], seM[1], ebM[1]);
      float g_g = fmaf(scr[128 + ra], seM[2], ebM[2]);
      float g_o = fmaf(scr[192 + ra], seM[3], ebM[3]);
      cM = sigm(g_f) * cM + sigm(g_i) * tanh_acc(g_g);
      float h = sigm(g_o) * tanh_acc(cM);
      s_Ahc[bM][phig]       = f2b(h);
      s_Ahc[bM][128 + phig] = f2b(cM);
      s_A8[bM][128 + phig]  = (char)(int)rintf(h * 127.f);
      s_encht[bM][phig][t]  = f2b(h);
    }
    __syncthreads();                                            // B2
    // ---- P_B: base_{t+1} (w0-3, transposed) ; ah-precompute (all waves) ----
    {
      i32x4 pa2 = *(const i32x4*)&s_A8[lane & 15][128 + ((lane >> 4) << 4)];
      i32x4 pa3 = *(const i32x4*)&s_A8[lane & 15][192 + ((lane >> 4) << 4)];
#pragma unroll
      for (int i = 0; i < 4; ++i) {
        i32x4 z = {0, 0, 0, 0};
        ahp[i] = MFMAI8(wg[3][i], pa3, MFMAI8(wg[2][i], pa2, z));
      }
    }
    if (w < 4) {
      if (t < T_ - 1) {                   // X prefetch: one full step early
        xf0 = Xr[(t + 1) * D_ + lane];
        xf1 = Xr[(t + 1) * D_ + 64 + lane];
      }
      f32x4 acc = {0.f, 0.f, 0.f, 0.f}, acc2 = {0.f, 0.f, 0.f, 0.f};
#pragma unroll
      for (int kt = 0; kt < 4; ++kt) {
        bf16x8 a = *(const bf16x8*)&s_Ahc[lane & 15][kt * 32 + ((lane >> 4) << 3)];
        acc = MFMA16(wb[kt], a, acc);
      }
#pragma unroll
      for (int kt = 4; kt < 8; ++kt) {
        bf16x8 a = *(const bf16x8*)&s_Ahc[lane & 15][kt * 32 + ((lane >> 4) << 3)];
        acc2 = MFMA16(wb[kt], a, acc2);
      }
      if ((lane & 15) < 4) {
        f32x4 v = acc + acc2 + webq;
        *(f32x4*)&s_base[lane & 15][(w << 4) + ((lane >> 4) << 2)] = v;
      }
    }
    __syncthreads();                                            // B3
  }
  // ---- final proj(T-1) (w4-7; s_Ahc still holds [h;c]_{T-1}) ----
  if (w >= 4) {
    f32x4 acc = {0.f, 0.f, 0.f, 0.f};
#pragma unroll
    for (int kt = 0; kt < 4; ++kt) {
      bf16x8 a = *(const bf16x8*)&s_Ahc[lane & 15][kt * 32 + ((lane >> 4) << 3)];
      acc = MFMA16(a, wp[kt], acc);
    }
    if (lane < 16) {
      int katt = (w - 4) * 16 + lane;
#pragma unroll
      for (int r = 0; r < 4; ++r) s_projT[r][katt][T_ - 1] = f2b(acc[r]);
    }
  }
  __syncthreads();

  // ====================== decoder ======================
  {
    int r = tid >> 7, j = tid & 127;
    s_Ahc[r][j] = 0; s_Ahc[r][128 + j] = 0; s_A8[r][j] = 0;
  }
  i32x4 wdg[2][8];                      // dec gates i8 (waves 4-7), nt=(w-4)*8+i
  bf16x8 wdc[8];                        // dc bf16 (waves 0-3)
  float yp = 0.f, yhd = 0.f;
  float sdC_p[8], db_p[8], dw_p[8];
  f32x4 wdbq = {0.f, 0.f, 0.f, 0.f};
  if (w >= 4) {
#pragma unroll
    for (int kt = 0; kt < 2; ++kt)
#pragma unroll
      for (int i = 0; i < 8; ++i)
        wdg[kt][i] = dec8[(kt * 32 + ((w - 4) * 8 + i)) * 64 + lane];
  } else {
#pragma unroll
    for (int kt = 0; kt < 8; ++kt)
      wdc[kt] = *(const bf16x8*)(f16 + WDDC_E + ((kt * 4 + w) * 64 + lane) * 8);
#pragma unroll
    for (int j = 0; j < 8; ++j) {
      sdC_p[j] = s_sd[lane + 64 * j] * C127;
      db_p[j]  = s_decb[lane + 64 * j];
      dw_p[j]  = s_dwih[lane + 64 * j];
    }
    wdbq = *(const f32x4*)&s_wdb[(w << 4) + ((lane >> 4) << 2)];
    yp = y_hist[(b0 + w) * T_ + (T_ - 1)];
    float pp = s_fcw[256 + lane] * y_hist[(b0 + w) * T_ + lane];
    yhd = wsum64(pp) + fc_b[0];
  }
  float dd0 = 0.f, dc0 = 0.f, dd1 = 0.f, dc1 = 0.f;   // d, cc (2 feats/lane)
  __syncthreads();

  for (int hs = 0; hs < HOR_; ++hs) {
    // ---- Phase A: w0-3 {cx0-half + fc-partial, dc GEMM}
    //              | w4-7 {gates GEMM, cx1-half + fc-partial} ----
    if (w >= 4) {
      i32x4 a0 = *(const i32x4*)&s_A8[lane & 15][ 0 + ((lane >> 4) << 4)];
      i32x4 a1 = *(const i32x4*)&s_A8[lane & 15][64 + ((lane >> 4) << 4)];
#pragma unroll
      for (int i = 0; i < 8; ++i) {
        i32x4 z = {0, 0, 0, 0};
        i32x4 ac = MFMAI8(wdg[1][i], a1, MFMAI8(wdg[0][i], a0, z));
        if ((lane & 15) < 4) {
          f32x4 v = {(float)ac[0], (float)ac[1], (float)ac[2], (float)ac[3]};
          *(f32x4*)&s_gates[lane & 15][(((w - 4) * 8 + i) << 4) + ((lane >> 4) << 2)] = v;
        }
      }
      if (hs > 0) {                      // cx1 half (features j>=64) for row w-4
        const int r = w - 4;
        float cx1a = 0.f, cx1b = 0.f;
        const short* e1p = &s_encht[r][lane + 64][0];
#pragma unroll 8
        for (int tp = 0; tp < 32; ++tp) {
          float2 bta = *(const float2*)&s_beta[r][2 * tp];
          short2 h1v = *(const short2*)&e1p[2 * tp];
          cx1a = fmaf(bta.x, b2f(h1v.x), cx1a);
          cx1b = fmaf(bta.y, b2f(h1v.y), cx1b);
        }
        float pf = s_fcw[192 + lane] * (cx1a + cx1b);
        pf = wsum64(pf);
        if (lane == 0) s_pf[r][1] = pf;
      }
    } else {
      if (hs > 0) {                      // cx0 half + dd-terms for row w
        float cx0a = 0.f, cx0b = 0.f;
        const short* e0p = &s_encht[w][lane][0];
#pragma unroll 8
        for (int tp = 0; tp < 32; ++tp) {
          float2 bta = *(const float2*)&s_beta[w][2 * tp];
          short2 h0v = *(const short2*)&e0p[2 * tp];
          cx0a = fmaf(bta.x, b2f(h0v.x), cx0a);
          cx0b = fmaf(bta.y, b2f(h0v.y), cx0b);
        }
        float pf = s_fcw[lane] * dd0 + s_fcw[64 + lane] * dd1
                 + s_fcw[128 + lane] * (cx0a + cx0b);
        pf = wsum64(pf);
        if (lane == 0) s_pf[w][0] = pf;
      }
      // dc GEMM (reads s_Ahc = d_hs written last Phase B)
      f32x4 acc = {0.f, 0.f, 0.f, 0.f}, acc2 = {0.f, 0.f, 0.f, 0.f};
#pragma unroll
      for (int kt = 0; kt < 4; ++kt) {
        bf16x8 a = *(const bf16x8*)&s_Ahc[lane & 15][kt * 32 + ((lane >> 4) << 3)];
        acc = MFMA16(wdc[kt], a, acc);
      }
#pragma unroll
      for (int kt = 4; kt < 8; ++kt) {
        bf16x8 a = *(const bf16x8*)&s_Ahc[lane & 15][kt * 32 + ((lane >> 4) << 3)];
        acc2 = MFMA16(wdc[kt], a, acc2);
      }
      if ((lane & 15) < 4) {
        f32x4 v = acc + acc2 + wdbq;
        *(f32x4*)&s_base[lane & 15][(w << 4) + ((lane >> 4) << 2)] = v;
      }
    }
    __syncthreads();                                            // B1
    // ---- Phase B: w0-3 {combine out(hs-1) + LSTM epilogue}
    //              | w4-7 {scores+softmax, prio} ----
    if (w < 4) {
      if (hs > 0) {                      // combine fc partials -> out, yp
        float o = s_pf[w][0] + s_pf[w][1] + yhd;   // LDS broadcast reads
        if (lane == 0) out[(b0 + w) * HOR_ + (hs - 1)] = o;
        yp = o;
      }
      float gi0 = s_gates[w][lane]       * sdC_p[0] + db_p[0] + yp * dw_p[0];
      float gi1 = s_gates[w][lane + 64]  * sdC_p[1] + db_p[1] + yp * dw_p[1];
      float gf0 = s_gates[w][lane + 128] * sdC_p[2] + db_p[2] + yp * dw_p[2];
      float gf1 = s_gates[w][lane + 192] * sdC_p[3] + db_p[3] + yp * dw_p[3];
      float gg0 = s_gates[w][lane + 256] * sdC_p[4] + db_p[4] + yp * dw_p[4];
      float gg1 = s_gates[w][lane + 320] * sdC_p[5] + db_p[5] + yp * dw_p[5];
      float go0 = s_gates[w][lane + 384] * sdC_p[6] + db_p[6] + yp * dw_p[6];
      float go1 = s_gates[w][lane + 448] * sdC_p[7] + db_p[7] + yp * dw_p[7];
      dc0 = sigm(gf0) * dc0 + sigm(gi0) * tanh_acc(gg0);
      dd0 = sigm(go0) * tanh_acc(dc0);
      dc1 = sigm(gf1) * dc1 + sigm(gi1) * tanh_acc(gg1);
      dd1 = sigm(go1) * tanh_acc(dc1);
      // state for next Phase A GEMMs
      s_Ahc[w][lane]       = f2b(dd0);
      s_Ahc[w][lane + 64]  = f2b(dd1);
      s_Ahc[w][lane + 128] = f2b(dc0);
      s_Ahc[w][lane + 192] = f2b(dc1);
      s_A8[w][lane]      = (char)(int)rintf(dd0 * 127.f);
      s_A8[w][lane + 64] = (char)(int)rintf(dd1 * 127.f);
    } else {
      __builtin_amdgcn_s_setprio(1);
      const int r = w - 4;
      float sA = 0.f, sB = 0.f, sC = 0.f, sD = 0.f;
#pragma unroll 4
      for (int k = 0; k < 64; k += 4) {
        sA += s_vd[k]     * tanh_acc(b2f(s_projT[r][k][lane])     + s_base[r][k]);
        sB += s_vd[k + 1] * tanh_acc(b2f(s_projT[r][k + 1][lane]) + s_base[r][k + 1]);
        sC += s_vd[k + 2] * tanh_acc(b2f(s_projT[r][k + 2][lane]) + s_base[r][k + 2]);
        sD += s_vd[k + 3] * tanh_acc(b2f(s_projT[r][k + 3][lane]) + s_base[r][k + 3]);
      }
      float s = (sA + sB) + (sC + sD);
      float e = fexp2(s * LOG2E);
      float ssum = wsum64(e);
      s_beta[r][lane] = e * frcp(ssum);
      __builtin_amdgcn_s_setprio(0);
    }
    __syncthreads();                                            // B2
  }
  // ---- tail: final context+fc+out for hs = HOR_-1 (w0-3, full) ----
  if (w < 4) {
    float cx0a = 0.f, cx0b = 0.f, cx1a = 0.f, cx1b = 0.f;
    const short* e0p = &s_encht[w][lane][0];
    const short* e1p = &s_encht[w][lane + 64][0];
#pragma unroll 8
    for (int tp = 0; tp < 32; ++tp) {
      float2 bta = *(const float2*)&s_beta[w][2 * tp];
      short2 h0v = *(const short2*)&e0p[2 * tp];
      short2 h1v = *(const short2*)&e1p[2 * tp];
      cx0a = fmaf(bta.x, b2f(h0v.x), cx0a); cx0b = fmaf(bta.y, b2f(h0v.y), cx0b);
      cx1a = fmaf(bta.x, b2f(h1v.x), cx1a); cx1b = fmaf(bta.y, b2f(h1v.y), cx1b);
    }
    float cx0 = cx0a + cx0b, cx1 = cx1a + cx1b;
    float pf = s_fcw[lane] * dd0 + s_fcw[64 + lane] * dd1
             + s_fcw[128 + lane] * cx0 + s_fcw[192 + lane] * cx1;
    pf = wsum64(pf);
    float o = pf + yhd;
    if (lane == 0) out[(b0 + w) * HOR_ + (HOR_ - 1)] = o;
  }
}

extern "C" void kernel_launch(void* const* d_in, const int* in_sizes, int n_in,
                              void* d_out, int out_size, void* d_ws, size_t ws_size,
                              hipStream_t stream) {
  (void)in_sizes; (void)n_in; (void)out_size; (void)ws_size;
  const float* X       = (const float*)d_in[0];
  const float* y_hist  = (const float*)d_in[1];
  const float* We_w    = (const float*)d_in[2];
  const float* We_b    = (const float*)d_in[3];
  const float* ve_w    = (const float*)d_in[4];
  // d_in[5] = ve_b : softmax-invariant, unused
  const float* enc_Wih = (const float*)d_in[6];
  const float* enc_Whh = (const float*)d_in[7];
  const float* enc_bih = (const float*)d_in[8];
  const float* enc_bhh = (const float*)d_in[9];
  const float* dec_Wih = (const float*)d_in[10];
  const float* dec_Whh = (const float*)d_in[11];
  const float* dec_bih = (const float*)d_in[12];
  const float* dec_bhh = (const float*)d_in[13];
  const float* Wd_w    = (const float*)d_in[14];
  const float* Wd_b    = (const float*)d_in[15];
  const float* vd_w    = (const float*)d_in[16];
  // d_in[17] = vd_b : softmax-invariant, unused
  const float* fc_w    = (const float*)d_in[18];
  const float* fc_b    = (const float*)d_in[19];

  char* ws8  = (char*)d_ws;
  float* out = (float*)d_out;

  prep_bf<<<160, 256, 0, stream>>>(We_w, Wd_w, ws8);
  prep_q <<<256, 256, 0, stream>>>(enc_Wih, enc_Whh, dec_Whh, ws8);
  da_rnn <<<B_ / BB, 512, 0, stream>>>(X, y_hist, We_w, We_b, ve_w,
                                       enc_bih, enc_bhh, dec_Wih, dec_bih, dec_bhh,
                                       Wd_b, vd_w, fc_w, fc_b, ws8, out);
}